// Round 1
// baseline (3175.201 us; speedup 1.0000x reference)
//
#include <hip/hip_runtime.h>

#define N_NODES   50000
#define N_EDGES   1600000
#define D_FEAT    64
#define N_SCALARS 4
#define H_DIM     68      // D_FEAT + N_SCALARS
#define HIDDEN    128
#define OUT_DIM   128

// ---------------------------------------------------------------------------
// Kernel 1: per-node precompute
//   U[n] = h[n] @ (W1a - W1b) + b1      (h = [x[n], scalars[batch[n]]])
//   V[n] = h[n] @ W1b
// so that edge layer-1 output z_e = U[dst] + V[src].
// Block = 128 threads (one per hidden unit), 32 nodes per block.
// W tiles staged in LDS once per block (2 * 68*128*4B = 69.6 KB).
// ---------------------------------------------------------------------------
__global__ __launch_bounds__(128) void node_precompute(
    const float* __restrict__ x, const float* __restrict__ scalars,
    const int* __restrict__ batch, const float* __restrict__ W1,
    const float* __restrict__ b1, float* __restrict__ U, float* __restrict__ V)
{
    __shared__ float Wd[H_DIM][HIDDEN];   // W1a - W1b
    __shared__ float Wb[H_DIM][HIDDEN];   // W1b
    __shared__ float hrow[32][H_DIM];

    const int tid = threadIdx.x;          // 0..127 = hidden unit
    for (int k = 0; k < H_DIM; ++k) {
        float wa = W1[k * HIDDEN + tid];
        float wb = W1[(k + H_DIM) * HIDDEN + tid];
        Wd[k][tid] = wa - wb;
        Wb[k][tid] = wb;
    }
    const int node0 = blockIdx.x * 32;
    for (int idx = tid; idx < 32 * H_DIM; idx += 128) {
        int i = idx / H_DIM;
        int k = idx - i * H_DIM;
        int n = node0 + i;
        float v = 0.f;
        if (n < N_NODES) {
            v = (k < D_FEAT) ? x[(size_t)n * D_FEAT + k]
                             : scalars[batch[n] * N_SCALARS + (k - D_FEAT)];
        }
        hrow[i][k] = v;
    }
    __syncthreads();

    const float bias = b1[tid];
    for (int i = 0; i < 32; ++i) {
        int n = node0 + i;
        if (n >= N_NODES) break;
        float au = bias, av = 0.f;
        #pragma unroll
        for (int k = 0; k < H_DIM; ++k) {
            float hk = hrow[i][k];                 // LDS broadcast (free)
            au = fmaf(hk, Wd[k][tid], au);         // 2-way bank alias (free)
            av = fmaf(hk, Wb[k][tid], av);
        }
        U[(size_t)n * HIDDEN + tid] = au;
        V[(size_t)n * HIDDEN + tid] = av;
    }
}

// ---------------------------------------------------------------------------
// Kernel 2: edge kernel.  32 threads per edge, float4 per thread.
//   r = relu(U[dst] + V[src]);  agg[dst] += r;  deg[dst] += 1
// ---------------------------------------------------------------------------
__global__ __launch_bounds__(256) void edge_kernel(
    const int* __restrict__ ei, const float* __restrict__ U,
    const float* __restrict__ V, float* __restrict__ agg, int* __restrict__ deg)
{
    const int t = blockIdx.x * 256 + threadIdx.x;
    const int e = t >> 5;
    if (e >= N_EDGES) return;
    const int lane = t & 31;

    const int src = ei[e];
    const int dst = ei[N_EDGES + e];

    const float4 u4 = *(const float4*)(U + (size_t)dst * HIDDEN + lane * 4);
    const float4 v4 = *(const float4*)(V + (size_t)src * HIDDEN + lane * 4);

    float rx = fmaxf(u4.x + v4.x, 0.f);
    float ry = fmaxf(u4.y + v4.y, 0.f);
    float rz = fmaxf(u4.z + v4.z, 0.f);
    float rw = fmaxf(u4.w + v4.w, 0.f);

    float* a = agg + (size_t)dst * HIDDEN + lane * 4;
    atomicAdd(a + 0, rx);
    atomicAdd(a + 1, ry);
    atomicAdd(a + 2, rz);
    atomicAdd(a + 3, rw);
    if (lane == 0) atomicAdd(deg + dst, 1);
}

// ---------------------------------------------------------------------------
// Kernel 3: out[n] = agg[n] @ W2 + deg[n] * b2
// Block = 128 threads, 32 nodes/block; W2 (64 KB) + 32 agg rows (16 KB) in LDS.
// ---------------------------------------------------------------------------
__global__ __launch_bounds__(128) void out_kernel(
    const float* __restrict__ agg, const int* __restrict__ deg,
    const float* __restrict__ W2, const float* __restrict__ b2,
    float* __restrict__ out)
{
    __shared__ float W2s[HIDDEN][OUT_DIM];
    __shared__ float aggs[32][HIDDEN];

    const int tid = threadIdx.x;          // output unit
    for (int k = 0; k < HIDDEN; ++k)
        W2s[k][tid] = W2[k * OUT_DIM + tid];

    const int node0 = blockIdx.x * 32;
    for (int idx = tid; idx < 32 * HIDDEN; idx += 128) {
        int i = idx >> 7;
        int k = idx & 127;
        int n = node0 + i;
        aggs[i][k] = (n < N_NODES) ? agg[(size_t)n * HIDDEN + k] : 0.f;
    }
    __syncthreads();

    const float bb = b2[tid];
    for (int i = 0; i < 32; ++i) {
        int n = node0 + i;
        if (n >= N_NODES) break;
        float acc = 0.f;
        #pragma unroll 16
        for (int k = 0; k < HIDDEN; ++k)
            acc = fmaf(aggs[i][k], W2s[k][tid], acc);
        out[(size_t)n * OUT_DIM + tid] = acc + bb * (float)deg[n];
    }
}

// ---------------------------------------------------------------------------
extern "C" void kernel_launch(void* const* d_in, const int* in_sizes, int n_in,
                              void* d_out, int out_size, void* d_ws, size_t ws_size,
                              hipStream_t stream)
{
    const float* x       = (const float*)d_in[0];
    const float* scalars = (const float*)d_in[1];
    const int*   batch   = (const int*)d_in[2];
    const int*   ei      = (const int*)d_in[3];
    const float* W1      = (const float*)d_in[4];
    const float* b1      = (const float*)d_in[5];
    const float* W2      = (const float*)d_in[6];
    const float* b2      = (const float*)d_in[7];
    float*       out     = (float*)d_out;

    // workspace layout: U | V | agg | deg   (~77 MB)
    float* U   = (float*)d_ws;
    float* V   = U + (size_t)N_NODES * HIDDEN;
    float* agg = V + (size_t)N_NODES * HIDDEN;
    int*   deg = (int*)(agg + (size_t)N_NODES * HIDDEN);

    // zero the accumulators (ws is poisoned 0xAA before every call)
    hipMemsetAsync(agg, 0,
                   (size_t)N_NODES * HIDDEN * sizeof(float) + (size_t)N_NODES * sizeof(int),
                   stream);

    node_precompute<<<(N_NODES + 31) / 32, 128, 0, stream>>>(
        x, scalars, batch, W1, b1, U, V);

    edge_kernel<<<(N_EDGES * 32 + 255) / 256, 256, 0, stream>>>(
        ei, U, V, agg, deg);

    out_kernel<<<(N_NODES + 31) / 32, 128, 0, stream>>>(
        agg, deg, W2, b2, out);
}

// Round 2
// 811.868 us; speedup vs baseline: 3.9110x; 3.9110x over previous
//
#include <hip/hip_runtime.h>

#define N_NODES   50000
#define N_EDGES   1600000
#define D_FEAT    64
#define N_SCALARS 4
#define H_DIM     68      // D_FEAT + N_SCALARS
#define HIDDEN    128
#define OUT_DIM   128

// ---------------------------------------------------------------------------
// Kernel 1: per-node precompute
//   U[n] = h[n] @ (W1a - W1b) + b1      (h = [x[n], scalars[batch[n]]])
//   V[n] = h[n] @ W1b
// Edge layer-1 output z_e = U[dst] + V[src].
// ---------------------------------------------------------------------------
__global__ __launch_bounds__(128) void node_precompute(
    const float* __restrict__ x, const float* __restrict__ scalars,
    const int* __restrict__ batch, const float* __restrict__ W1,
    const float* __restrict__ b1, float* __restrict__ U, float* __restrict__ V)
{
    __shared__ float Wd[H_DIM][HIDDEN];   // W1a - W1b
    __shared__ float Wb[H_DIM][HIDDEN];   // W1b
    __shared__ float hrow[32][H_DIM];

    const int tid = threadIdx.x;          // 0..127 = hidden unit
    for (int k = 0; k < H_DIM; ++k) {
        float wa = W1[k * HIDDEN + tid];
        float wb = W1[(k + H_DIM) * HIDDEN + tid];
        Wd[k][tid] = wa - wb;
        Wb[k][tid] = wb;
    }
    const int node0 = blockIdx.x * 32;
    for (int idx = tid; idx < 32 * H_DIM; idx += 128) {
        int i = idx / H_DIM;
        int k = idx - i * H_DIM;
        int n = node0 + i;
        float v = 0.f;
        if (n < N_NODES) {
            v = (k < D_FEAT) ? x[(size_t)n * D_FEAT + k]
                             : scalars[batch[n] * N_SCALARS + (k - D_FEAT)];
        }
        hrow[i][k] = v;
    }
    __syncthreads();

    const float bias = b1[tid];
    for (int i = 0; i < 32; ++i) {
        int n = node0 + i;
        if (n >= N_NODES) break;
        float au = bias, av = 0.f;
        #pragma unroll
        for (int k = 0; k < H_DIM; ++k) {
            float hk = hrow[i][k];
            au = fmaf(hk, Wd[k][tid], au);
            av = fmaf(hk, Wb[k][tid], av);
        }
        U[(size_t)n * HIDDEN + tid] = au;
        V[(size_t)n * HIDDEN + tid] = av;
    }
}

// ---------------------------------------------------------------------------
// Counting sort of edges by dst: histogram -> scan -> scatter(src only).
// ---------------------------------------------------------------------------
__global__ __launch_bounds__(256) void hist_kernel(
    const int* __restrict__ ei, int* __restrict__ deg)
{
    int e = blockIdx.x * 256 + threadIdx.x;
    if (e >= N_EDGES) return;
    atomicAdd(&deg[ei[N_EDGES + e]], 1);
}

// single-block exclusive scan over 50000 bins; writes off[0..N] and cursor.
__global__ __launch_bounds__(1024) void scan_kernel(
    const int* __restrict__ deg, int* __restrict__ off, int* __restrict__ cursor)
{
    __shared__ int partial[1024];
    const int T = 1024;
    const int tid = threadIdx.x;
    const int per = (N_NODES + T - 1) / T;           // 49
    const int start = tid * per;
    const int end   = min(start + per, N_NODES);

    int s = 0;
    for (int i = start; i < end; ++i) s += deg[i];
    partial[tid] = s;
    __syncthreads();
    for (int d = 1; d < T; d <<= 1) {                // Hillis-Steele inclusive
        int v = (tid >= d) ? partial[tid - d] : 0;
        __syncthreads();
        partial[tid] += v;
        __syncthreads();
    }
    int run = (tid == 0) ? 0 : partial[tid - 1];
    for (int i = start; i < end; ++i) {
        off[i] = run; cursor[i] = run; run += deg[i];
    }
    if (tid == T - 1) off[N_NODES] = run;            // == N_EDGES
}

__global__ __launch_bounds__(256) void scatter_kernel(
    const int* __restrict__ ei, int* __restrict__ cursor, int* __restrict__ sorted_src)
{
    int e = blockIdx.x * 256 + threadIdx.x;
    if (e >= N_EDGES) return;
    int src = ei[e];
    int dst = ei[N_EDGES + e];
    int pos = atomicAdd(&cursor[dst], 1);
    sorted_src[pos] = src;
}

// ---------------------------------------------------------------------------
// Aggregate: one wave (64 lanes, float2/lane) per node.
//   agg[n] = sum over edges(dst==n) of relu(U[n] + V[src])   — no atomics.
// ---------------------------------------------------------------------------
__global__ __launch_bounds__(256) void aggregate_kernel(
    const int* __restrict__ off, const int* __restrict__ sorted_src,
    const float* __restrict__ U, const float* __restrict__ V,
    float* __restrict__ agg)
{
    const int wave = (blockIdx.x * 256 + threadIdx.x) >> 6;
    const int lane = threadIdx.x & 63;
    if (wave >= N_NODES) return;
    const int n = wave;

    const int beg = off[n], end = off[n + 1];
    const float2 u2 = *(const float2*)(U + (size_t)n * HIDDEN + lane * 2);
    float ax = 0.f, ay = 0.f;

    int k = beg;
    for (; k + 1 < end; k += 2) {                    // 2 independent loads in flight
        int s0 = sorted_src[k];
        int s1 = sorted_src[k + 1];
        float2 a = *(const float2*)(V + (size_t)s0 * HIDDEN + lane * 2);
        float2 b = *(const float2*)(V + (size_t)s1 * HIDDEN + lane * 2);
        ax += fmaxf(u2.x + a.x, 0.f) + fmaxf(u2.x + b.x, 0.f);
        ay += fmaxf(u2.y + a.y, 0.f) + fmaxf(u2.y + b.y, 0.f);
    }
    if (k < end) {
        int s0 = sorted_src[k];
        float2 a = *(const float2*)(V + (size_t)s0 * HIDDEN + lane * 2);
        ax += fmaxf(u2.x + a.x, 0.f);
        ay += fmaxf(u2.y + a.y, 0.f);
    }
    *(float2*)(agg + (size_t)n * HIDDEN + lane * 2) = make_float2(ax, ay);
}

// ---------------------------------------------------------------------------
// out[n] = agg[n] @ W2 + (off[n+1]-off[n]) * b2
// ---------------------------------------------------------------------------
__global__ __launch_bounds__(128) void out_kernel(
    const float* __restrict__ agg, const int* __restrict__ off,
    const float* __restrict__ W2, const float* __restrict__ b2,
    float* __restrict__ out)
{
    __shared__ float W2s[HIDDEN][OUT_DIM];
    __shared__ float aggs[32][HIDDEN];

    const int tid = threadIdx.x;          // output unit
    for (int k = 0; k < HIDDEN; ++k)
        W2s[k][tid] = W2[k * OUT_DIM + tid];

    const int node0 = blockIdx.x * 32;
    for (int idx = tid; idx < 32 * HIDDEN; idx += 128) {
        int i = idx >> 7;
        int k = idx & 127;
        int n = node0 + i;
        aggs[i][k] = (n < N_NODES) ? agg[(size_t)n * HIDDEN + k] : 0.f;
    }
    __syncthreads();

    const float bb = b2[tid];
    for (int i = 0; i < 32; ++i) {
        int n = node0 + i;
        if (n >= N_NODES) break;
        float acc = 0.f;
        #pragma unroll 16
        for (int k = 0; k < HIDDEN; ++k)
            acc = fmaf(aggs[i][k], W2s[k][tid], acc);
        out[(size_t)n * OUT_DIM + tid] = acc + bb * (float)(off[n + 1] - off[n]);
    }
}

// ---------------------------------------------------------------------------
extern "C" void kernel_launch(void* const* d_in, const int* in_sizes, int n_in,
                              void* d_out, int out_size, void* d_ws, size_t ws_size,
                              hipStream_t stream)
{
    const float* x       = (const float*)d_in[0];
    const float* scalars = (const float*)d_in[1];
    const int*   batch   = (const int*)d_in[2];
    const int*   ei      = (const int*)d_in[3];
    const float* W1      = (const float*)d_in[4];
    const float* b1      = (const float*)d_in[5];
    const float* W2      = (const float*)d_in[6];
    const float* b2      = (const float*)d_in[7];
    float*       out     = (float*)d_out;

    // ws layout: U | V | agg | sorted_src | deg | off | cursor   (~84 MB)
    float* U          = (float*)d_ws;
    float* V          = U + (size_t)N_NODES * HIDDEN;
    float* agg        = V + (size_t)N_NODES * HIDDEN;
    int*   sorted_src = (int*)(agg + (size_t)N_NODES * HIDDEN);
    int*   deg        = sorted_src + N_EDGES;
    int*   off        = deg + N_NODES;          // N_NODES+1 entries
    int*   cursor     = off + N_NODES + 1;

    hipMemsetAsync(deg, 0, N_NODES * sizeof(int), stream);

    node_precompute<<<(N_NODES + 31) / 32, 128, 0, stream>>>(
        x, scalars, batch, W1, b1, U, V);

    hist_kernel<<<(N_EDGES + 255) / 256, 256, 0, stream>>>(ei, deg);
    scan_kernel<<<1, 1024, 0, stream>>>(deg, off, cursor);
    scatter_kernel<<<(N_EDGES + 255) / 256, 256, 0, stream>>>(ei, cursor, sorted_src);

    aggregate_kernel<<<(N_NODES * 64 + 255) / 256, 256, 0, stream>>>(
        off, sorted_src, U, V, agg);

    out_kernel<<<(N_NODES + 31) / 32, 128, 0, stream>>>(
        agg, off, W2, b2, out);
}

// Round 3
// 603.726 us; speedup vs baseline: 5.2593x; 1.3448x over previous
//
#include <hip/hip_runtime.h>

#define N_NODES   50000
#define N_EDGES   1600000
#define D_FEAT    64
#define N_SCALARS 4
#define H_DIM     68      // D_FEAT + N_SCALARS
#define HIDDEN    128
#define OUT_DIM   128
#define UV_DIM    256     // [U | V] concatenated per node

// ---------------------------------------------------------------------------
// Wf[k][j] = (j<128) ? W1[k][j] - W1[k+68][j] : W1[k+68][j-128]
// so  UV[n] = h[n] @ Wf  gives U (cols 0..127, +b1 in epilogue) and V.
// ---------------------------------------------------------------------------
__global__ __launch_bounds__(256) void wf_prep(const float* __restrict__ W1,
                                               float* __restrict__ Wf)
{
    int idx = blockIdx.x * 256 + threadIdx.x;
    if (idx >= H_DIM * UV_DIM) return;
    int k = idx >> 8;
    int j = idx & 255;
    float wb = W1[(k + H_DIM) * HIDDEN + (j & 127)];
    Wf[idx] = (j < HIDDEN) ? (W1[k * HIDDEN + j] - wb) : wb;
}

// ---------------------------------------------------------------------------
// GEMM1: UV[64-node tile][64-col tile] = h @ Wf (+b1 on U half).
// 256 threads, 4x4 register tile, A staged transposed (pad +4).
// ---------------------------------------------------------------------------
__global__ __launch_bounds__(256) void gemm_uv(
    const float* __restrict__ x, const float* __restrict__ scalars,
    const int* __restrict__ batch, const float* __restrict__ Wf,
    const float* __restrict__ b1, float* __restrict__ UV)
{
    __shared__ float As[H_DIM][68];   // [k][m], pad 64->68
    __shared__ float Bs[H_DIM][68];   // [k][n], pad 64->68

    const int node0 = blockIdx.x * 64;
    const int col0t = blockIdx.y * 64;
    const int tid   = threadIdx.x;

    // stage A transposed: m-fast so LDS writes are conflict-free
    for (int idx = tid; idx < 64 * H_DIM; idx += 256) {
        int m = idx & 63;
        int k = idx >> 6;
        int n = node0 + m;
        float v = 0.f;
        if (n < N_NODES)
            v = (k < D_FEAT) ? x[(size_t)n * D_FEAT + k]
                             : scalars[batch[n] * N_SCALARS + (k - D_FEAT)];
        As[k][m] = v;
    }
    // stage B: n-fast (coalesced global, conflict-free LDS)
    for (int idx = tid; idx < 64 * H_DIM; idx += 256) {
        int n = idx & 63;
        int k = idx >> 6;
        Bs[k][n] = Wf[k * UV_DIM + col0t + n];
    }
    __syncthreads();

    const int tx = tid & 15, ty = tid >> 4;
    const int m0 = ty * 4, n0 = tx * 4;
    float acc[4][4] = {};

    #pragma unroll 4
    for (int k = 0; k < H_DIM; ++k) {
        float4 av = *(const float4*)&As[k][m0];
        float4 bv = *(const float4*)&Bs[k][n0];
        float aa[4] = {av.x, av.y, av.z, av.w};
        float bb[4] = {bv.x, bv.y, bv.z, bv.w};
        #pragma unroll
        for (int i = 0; i < 4; ++i)
            #pragma unroll
            for (int j = 0; j < 4; ++j)
                acc[i][j] = fmaf(aa[i], bb[j], acc[i][j]);
    }

    const int colbase = col0t + n0;
    float4 bias = make_float4(0.f, 0.f, 0.f, 0.f);
    if (colbase < HIDDEN) bias = *(const float4*)&b1[colbase];
    #pragma unroll
    for (int i = 0; i < 4; ++i) {
        int n = node0 + m0 + i;
        if (n >= N_NODES) continue;
        float4 o = make_float4(acc[i][0] + bias.x, acc[i][1] + bias.y,
                               acc[i][2] + bias.z, acc[i][3] + bias.w);
        *(float4*)&UV[(size_t)n * UV_DIM + colbase] = o;
    }
}

// ---------------------------------------------------------------------------
// Counting sort of edges by dst.
// ---------------------------------------------------------------------------
__global__ __launch_bounds__(256) void hist_kernel(
    const int* __restrict__ ei, int* __restrict__ deg)
{
    int e = blockIdx.x * 256 + threadIdx.x;
    if (e >= N_EDGES) return;
    atomicAdd(&deg[ei[N_EDGES + e]], 1);
}

__global__ __launch_bounds__(1024) void scan_kernel(
    const int* __restrict__ deg, int* __restrict__ off, int* __restrict__ cursor)
{
    __shared__ int partial[1024];
    const int T = 1024;
    const int tid = threadIdx.x;
    const int per = (N_NODES + T - 1) / T;
    const int start = tid * per;
    const int end   = min(start + per, N_NODES);

    int s = 0;
    for (int i = start; i < end; ++i) s += deg[i];
    partial[tid] = s;
    __syncthreads();
    for (int d = 1; d < T; d <<= 1) {
        int v = (tid >= d) ? partial[tid - d] : 0;
        __syncthreads();
        partial[tid] += v;
        __syncthreads();
    }
    int run = (tid == 0) ? 0 : partial[tid - 1];
    for (int i = start; i < end; ++i) {
        off[i] = run; cursor[i] = run; run += deg[i];
    }
    if (tid == T - 1) off[N_NODES] = run;
}

__global__ __launch_bounds__(256) void scatter_kernel(
    const int* __restrict__ ei, int* __restrict__ cursor, int* __restrict__ sorted_src)
{
    int e = blockIdx.x * 256 + threadIdx.x;
    if (e >= N_EDGES) return;
    int src = ei[e];
    int dst = ei[N_EDGES + e];
    int pos = atomicAdd(&cursor[dst], 1);
    sorted_src[pos] = src;
}

// ---------------------------------------------------------------------------
// Aggregate: 32 lanes per node, float4/lane, 4-edge unroll; no atomics.
//   agg[n] = sum over edges(dst==n) of relu(U[n] + V[src])
// ---------------------------------------------------------------------------
__global__ __launch_bounds__(256) void aggregate_kernel(
    const int* __restrict__ off, const int* __restrict__ sorted_src,
    const float* __restrict__ UV, float* __restrict__ agg)
{
    const int g    = blockIdx.x * 256 + threadIdx.x;
    const int node = g >> 5;
    const int lane = g & 31;
    if (node >= N_NODES) return;

    const int beg = off[node], end = off[node + 1];
    const float4 u4 = *(const float4*)(UV + (size_t)node * UV_DIM + lane * 4);
    float4 acc = make_float4(0.f, 0.f, 0.f, 0.f);

    int k = beg;
    for (; k + 4 <= end; k += 4) {
        int s0 = sorted_src[k + 0];
        int s1 = sorted_src[k + 1];
        int s2 = sorted_src[k + 2];
        int s3 = sorted_src[k + 3];
        float4 v0 = *(const float4*)(UV + (size_t)s0 * UV_DIM + HIDDEN + lane * 4);
        float4 v1 = *(const float4*)(UV + (size_t)s1 * UV_DIM + HIDDEN + lane * 4);
        float4 v2 = *(const float4*)(UV + (size_t)s2 * UV_DIM + HIDDEN + lane * 4);
        float4 v3 = *(const float4*)(UV + (size_t)s3 * UV_DIM + HIDDEN + lane * 4);
        acc.x += fmaxf(u4.x + v0.x, 0.f) + fmaxf(u4.x + v1.x, 0.f)
               + fmaxf(u4.x + v2.x, 0.f) + fmaxf(u4.x + v3.x, 0.f);
        acc.y += fmaxf(u4.y + v0.y, 0.f) + fmaxf(u4.y + v1.y, 0.f)
               + fmaxf(u4.y + v2.y, 0.f) + fmaxf(u4.y + v3.y, 0.f);
        acc.z += fmaxf(u4.z + v0.z, 0.f) + fmaxf(u4.z + v1.z, 0.f)
               + fmaxf(u4.z + v2.z, 0.f) + fmaxf(u4.z + v3.z, 0.f);
        acc.w += fmaxf(u4.w + v0.w, 0.f) + fmaxf(u4.w + v1.w, 0.f)
               + fmaxf(u4.w + v2.w, 0.f) + fmaxf(u4.w + v3.w, 0.f);
    }
    for (; k < end; ++k) {
        int s0 = sorted_src[k];
        float4 v0 = *(const float4*)(UV + (size_t)s0 * UV_DIM + HIDDEN + lane * 4);
        acc.x += fmaxf(u4.x + v0.x, 0.f);
        acc.y += fmaxf(u4.y + v0.y, 0.f);
        acc.z += fmaxf(u4.z + v0.z, 0.f);
        acc.w += fmaxf(u4.w + v0.w, 0.f);
    }
    *(float4*)(agg + (size_t)node * HIDDEN + lane * 4) = acc;
}

// ---------------------------------------------------------------------------
// GEMM2: out[64-node tile][64-col tile] = agg @ W2 + deg*b2.
// ---------------------------------------------------------------------------
__global__ __launch_bounds__(256) void gemm_out(
    const float* __restrict__ agg, const int* __restrict__ deg,
    const float* __restrict__ W2, const float* __restrict__ b2,
    float* __restrict__ out)
{
    __shared__ float As[HIDDEN][68];
    __shared__ float Bs[HIDDEN][68];

    const int node0 = blockIdx.x * 64;
    const int col0t = blockIdx.y * 64;
    const int tid   = threadIdx.x;

    for (int idx = tid; idx < 64 * HIDDEN; idx += 256) {
        int m = idx & 63;
        int k = idx >> 6;
        int n = node0 + m;
        As[k][m] = (n < N_NODES) ? agg[(size_t)n * HIDDEN + k] : 0.f;
    }
    for (int idx = tid; idx < 64 * HIDDEN; idx += 256) {
        int n = idx & 63;
        int k = idx >> 6;
        Bs[k][n] = W2[k * OUT_DIM + col0t + n];
    }
    __syncthreads();

    const int tx = tid & 15, ty = tid >> 4;
    const int m0 = ty * 4, n0 = tx * 4;
    float acc[4][4] = {};

    #pragma unroll 4
    for (int k = 0; k < HIDDEN; ++k) {
        float4 av = *(const float4*)&As[k][m0];
        float4 bv = *(const float4*)&Bs[k][n0];
        float aa[4] = {av.x, av.y, av.z, av.w};
        float bb[4] = {bv.x, bv.y, bv.z, bv.w};
        #pragma unroll
        for (int i = 0; i < 4; ++i)
            #pragma unroll
            for (int j = 0; j < 4; ++j)
                acc[i][j] = fmaf(aa[i], bb[j], acc[i][j]);
    }

    const int colbase = col0t + n0;
    const float4 b2v = *(const float4*)&b2[colbase];
    #pragma unroll
    for (int i = 0; i < 4; ++i) {
        int n = node0 + m0 + i;
        if (n >= N_NODES) continue;
        float dg = (float)deg[n];
        float4 o = make_float4(acc[i][0] + b2v.x * dg, acc[i][1] + b2v.y * dg,
                               acc[i][2] + b2v.z * dg, acc[i][3] + b2v.w * dg);
        *(float4*)&out[(size_t)n * OUT_DIM + colbase] = o;
    }
}

// ---------------------------------------------------------------------------
extern "C" void kernel_launch(void* const* d_in, const int* in_sizes, int n_in,
                              void* d_out, int out_size, void* d_ws, size_t ws_size,
                              hipStream_t stream)
{
    const float* x       = (const float*)d_in[0];
    const float* scalars = (const float*)d_in[1];
    const int*   batch   = (const int*)d_in[2];
    const int*   ei      = (const int*)d_in[3];
    const float* W1      = (const float*)d_in[4];
    const float* b1      = (const float*)d_in[5];
    const float* W2      = (const float*)d_in[6];
    const float* b2      = (const float*)d_in[7];
    float*       out     = (float*)d_out;

    // ws layout: UV | agg | sorted_src | deg | off | cursor | Wf  (~84 MB)
    float* UV         = (float*)d_ws;
    float* agg        = UV + (size_t)N_NODES * UV_DIM;
    int*   sorted_src = (int*)(agg + (size_t)N_NODES * HIDDEN);
    int*   deg        = sorted_src + N_EDGES;
    int*   off        = deg + N_NODES;          // N_NODES+1 entries
    int*   cursor     = off + N_NODES + 1;
    float* Wf         = (float*)(cursor + N_NODES);

    hipMemsetAsync(deg, 0, N_NODES * sizeof(int), stream);

    wf_prep<<<(H_DIM * UV_DIM + 255) / 256, 256, 0, stream>>>(W1, Wf);

    gemm_uv<<<dim3((N_NODES + 63) / 64, UV_DIM / 64), 256, 0, stream>>>(
        x, scalars, batch, Wf, b1, UV);

    hist_kernel<<<(N_EDGES + 255) / 256, 256, 0, stream>>>(ei, deg);
    scan_kernel<<<1, 1024, 0, stream>>>(deg, off, cursor);
    scatter_kernel<<<(N_EDGES + 255) / 256, 256, 0, stream>>>(ei, cursor, sorted_src);

    aggregate_kernel<<<(N_NODES * 32 + 255) / 256, 256, 0, stream>>>(
        off, sorted_src, UV, agg);

    gemm_out<<<dim3((N_NODES + 63) / 64, OUT_DIM / 64), 256, 0, stream>>>(
        agg, deg, W2, b2, out);
}

// Round 4
// 332.375 us; speedup vs baseline: 9.5531x; 1.8164x over previous
//
#include <hip/hip_runtime.h>

#define N_NODES   50000
#define N_EDGES   1600000
#define D_FEAT    64
#define N_SCALARS 4
#define H_DIM     68      // D_FEAT + N_SCALARS
#define HIDDEN    128
#define OUT_DIM   128
#define UV_DIM    256     // [U | V] concatenated per node

#define SLICE_SH  6                         // 64 nodes per slice
#define SLICE_N   (1 << SLICE_SH)
#define NSLICE    ((N_NODES + SLICE_N - 1) >> SLICE_SH)   // 782
#define CAP       2560                      // per-slice capacity (mean 2048, sd 45)
#define CHUNK     8192                      // edges per bin_kernel block

// ---------------------------------------------------------------------------
// Wf[k][j] = (j<128) ? W1[k][j] - W1[k+68][j] : W1[k+68][j-128]
// so  UV[n] = h[n] @ Wf  gives U (cols 0..127, +b1 in epilogue) and V.
// ---------------------------------------------------------------------------
__global__ __launch_bounds__(256) void wf_prep(const float* __restrict__ W1,
                                               float* __restrict__ Wf)
{
    int idx = blockIdx.x * 256 + threadIdx.x;
    if (idx >= H_DIM * UV_DIM) return;
    int k = idx >> 8;
    int j = idx & 255;
    float wb = W1[(k + H_DIM) * HIDDEN + (j & 127)];
    Wf[idx] = (j < HIDDEN) ? (W1[k * HIDDEN + j] - wb) : wb;
}

// ---------------------------------------------------------------------------
// GEMM1: UV[64-node tile][64-col tile] = h @ Wf (+b1 on U half).
// ---------------------------------------------------------------------------
__global__ __launch_bounds__(256) void gemm_uv(
    const float* __restrict__ x, const float* __restrict__ scalars,
    const int* __restrict__ batch, const float* __restrict__ Wf,
    const float* __restrict__ b1, float* __restrict__ UV)
{
    __shared__ float As[H_DIM][68];
    __shared__ float Bs[H_DIM][68];

    const int node0 = blockIdx.x * 64;
    const int col0t = blockIdx.y * 64;
    const int tid   = threadIdx.x;

    for (int idx = tid; idx < 64 * H_DIM; idx += 256) {
        int m = idx & 63;
        int k = idx >> 6;
        int n = node0 + m;
        float v = 0.f;
        if (n < N_NODES)
            v = (k < D_FEAT) ? x[(size_t)n * D_FEAT + k]
                             : scalars[batch[n] * N_SCALARS + (k - D_FEAT)];
        As[k][m] = v;
    }
    for (int idx = tid; idx < 64 * H_DIM; idx += 256) {
        int n = idx & 63;
        int k = idx >> 6;
        Bs[k][n] = Wf[k * UV_DIM + col0t + n];
    }
    __syncthreads();

    const int tx = tid & 15, ty = tid >> 4;
    const int m0 = ty * 4, n0 = tx * 4;
    float acc[4][4] = {};

    #pragma unroll 4
    for (int k = 0; k < H_DIM; ++k) {
        float4 av = *(const float4*)&As[k][m0];
        float4 bv = *(const float4*)&Bs[k][n0];
        float aa[4] = {av.x, av.y, av.z, av.w};
        float bb[4] = {bv.x, bv.y, bv.z, bv.w};
        #pragma unroll
        for (int i = 0; i < 4; ++i)
            #pragma unroll
            for (int j = 0; j < 4; ++j)
                acc[i][j] = fmaf(aa[i], bb[j], acc[i][j]);
    }

    const int colbase = col0t + n0;
    float4 bias = make_float4(0.f, 0.f, 0.f, 0.f);
    if (colbase < HIDDEN) bias = *(const float4*)&b1[colbase];
    #pragma unroll
    for (int i = 0; i < 4; ++i) {
        int n = node0 + m0 + i;
        if (n >= N_NODES) continue;
        float4 o = make_float4(acc[i][0] + bias.x, acc[i][1] + bias.y,
                               acc[i][2] + bias.z, acc[i][3] + bias.w);
        *(float4*)&UV[(size_t)n * UV_DIM + colbase] = o;
    }
}

// ---------------------------------------------------------------------------
// bin_kernel: per-block LDS counting sort by slice (dst>>6), then append each
// slice's run to glist[slice*CAP ...] via one global atomicAdd per slice.
// Entries packed (dst<<16)|src (both < 65536).
// ---------------------------------------------------------------------------
__global__ __launch_bounds__(256) void bin_kernel(
    const int* __restrict__ ei, int* __restrict__ tails,
    unsigned* __restrict__ glist)
{
    __shared__ unsigned buf[CHUNK];       // 32 KB
    __shared__ int hist[NSLICE];
    __shared__ int binStart[NSLICE];
    __shared__ int cursor[NSLICE];
    __shared__ int gbase[NSLICE];
    __shared__ int scanTmp[256];

    const int tid = threadIdx.x;
    const int e0  = blockIdx.x * CHUNK;
    const int nE  = min(CHUNK, N_EDGES - e0);

    for (int i = tid; i < NSLICE; i += 256) hist[i] = 0;
    __syncthreads();

    // load + pack + histogram (keep entries in registers)
    unsigned ent[CHUNK / 256];
    #pragma unroll
    for (int j = 0; j < CHUNK / 256; ++j) {
        int e = e0 + tid + j * 256;
        if (e < N_EDGES) {
            unsigned s = (unsigned)ei[e];
            unsigned d = (unsigned)ei[N_EDGES + e];
            ent[j] = (d << 16) | s;
            atomicAdd(&hist[d >> SLICE_SH], 1);
        } else {
            ent[j] = 0xFFFFFFFFu;
        }
    }
    __syncthreads();

    // exclusive scan of hist (256 threads x 4 bins)
    const int base4 = tid * 4;
    int loc[4];
    int sum = 0;
    #pragma unroll
    for (int k = 0; k < 4; ++k) {
        int b = base4 + k;
        loc[k] = (b < NSLICE) ? hist[b] : 0;
        sum += loc[k];
    }
    scanTmp[tid] = sum;
    __syncthreads();
    for (int d = 1; d < 256; d <<= 1) {
        int v = (tid >= d) ? scanTmp[tid - d] : 0;
        __syncthreads();
        scanTmp[tid] += v;
        __syncthreads();
    }
    int run = (tid == 0) ? 0 : scanTmp[tid - 1];
    #pragma unroll
    for (int k = 0; k < 4; ++k) {
        int b = base4 + k;
        if (b < NSLICE) { binStart[b] = run; cursor[b] = run; run += loc[k]; }
    }
    __syncthreads();

    // scatter into LDS buf, grouped by slice
    #pragma unroll
    for (int j = 0; j < CHUNK / 256; ++j) {
        if (ent[j] != 0xFFFFFFFFu) {
            int sl = (int)(ent[j] >> (16 + SLICE_SH));
            int pos = atomicAdd(&cursor[sl], 1);
            buf[pos] = ent[j];
        }
    }
    __syncthreads();

    // reserve global ranges: one atomic per non-empty slice
    for (int s = tid; s < NSLICE; s += 256) {
        int c = hist[s];
        if (c > 0) gbase[s] = atomicAdd(&tails[s], c);
    }
    __syncthreads();

    // cooperative copy: consecutive lanes -> consecutive global addresses
    for (int i = tid; i < nE; i += 256) {
        unsigned e = buf[i];
        int sl = (int)(e >> (16 + SLICE_SH));
        int di = gbase[sl] + (i - binStart[sl]);
        if (di < CAP) glist[(size_t)sl * CAP + di] = e;
    }
}

// ---------------------------------------------------------------------------
// aggregate_slice: one block per 64-node slice.  LDS counting sort by
// dst&63, then each wave owns node-groups: register accumulation of
// relu(U[n] + V[src]) over the group's edges.  No atomics, direct agg write.
// ---------------------------------------------------------------------------
__global__ __launch_bounds__(256) void aggregate_slice(
    const unsigned* __restrict__ glist, const int* __restrict__ tails,
    const float* __restrict__ UV, float* __restrict__ agg,
    int* __restrict__ deg)
{
    __shared__ int h64[64];        // per-node counts (preserved)
    __shared__ int start64[64];    // exclusive starts
    __shared__ int cur64[64];
    __shared__ int scanB[64];
    __shared__ unsigned sbuf[CAP]; // src ids grouped by local node (10 KB)

    const int slice = blockIdx.x;
    const int node0 = slice << SLICE_SH;
    const int tid   = threadIdx.x;
    const unsigned* lst = glist + (size_t)slice * CAP;
    const int cnt = min(tails[slice], CAP);

    if (tid < 64) h64[tid] = 0;
    __syncthreads();
    for (int i = tid; i < cnt; i += 256)
        atomicAdd(&h64[(lst[i] >> 16) & 63], 1);
    __syncthreads();
    if (tid < 64) scanB[tid] = h64[tid];
    __syncthreads();
    for (int d = 1; d < 64; d <<= 1) {
        int v = 0;
        if (tid < 64 && tid >= d) v = scanB[tid - d];
        __syncthreads();
        if (tid < 64) scanB[tid] += v;
        __syncthreads();
    }
    if (tid < 64) {
        start64[tid] = scanB[tid] - h64[tid];
        cur64[tid]   = scanB[tid] - h64[tid];
    }
    __syncthreads();
    for (int i = tid; i < cnt; i += 256) {
        unsigned e = lst[i];
        int dl = (e >> 16) & 63;
        int p = atomicAdd(&cur64[dl], 1);
        sbuf[p] = e & 0xFFFFu;
    }
    __syncthreads();

    const int wave = tid >> 6;
    const int lane = tid & 63;
    const int c2   = lane * 2;

    for (int dl = wave; dl < 64; dl += 4) {
        int n = node0 + dl;
        if (n >= N_NODES) continue;
        const int gb = start64[dl];
        const int gc = h64[dl];
        const float2 u = *(const float2*)&UV[(size_t)n * UV_DIM + c2];
        float ax = 0.f, ay = 0.f;

        int p = gb, pe = gb + gc;
        for (; p + 4 <= pe; p += 4) {
            int s0 = sbuf[p + 0];
            int s1 = sbuf[p + 1];
            int s2 = sbuf[p + 2];
            int s3 = sbuf[p + 3];
            float2 v0 = *(const float2*)&UV[(size_t)s0 * UV_DIM + HIDDEN + c2];
            float2 v1 = *(const float2*)&UV[(size_t)s1 * UV_DIM + HIDDEN + c2];
            float2 v2 = *(const float2*)&UV[(size_t)s2 * UV_DIM + HIDDEN + c2];
            float2 v3 = *(const float2*)&UV[(size_t)s3 * UV_DIM + HIDDEN + c2];
            ax += fmaxf(u.x + v0.x, 0.f) + fmaxf(u.x + v1.x, 0.f)
                + fmaxf(u.x + v2.x, 0.f) + fmaxf(u.x + v3.x, 0.f);
            ay += fmaxf(u.y + v0.y, 0.f) + fmaxf(u.y + v1.y, 0.f)
                + fmaxf(u.y + v2.y, 0.f) + fmaxf(u.y + v3.y, 0.f);
        }
        for (; p < pe; ++p) {
            int s0 = sbuf[p];
            float2 v0 = *(const float2*)&UV[(size_t)s0 * UV_DIM + HIDDEN + c2];
            ax += fmaxf(u.x + v0.x, 0.f);
            ay += fmaxf(u.y + v0.y, 0.f);
        }
        *(float2*)&agg[(size_t)n * HIDDEN + c2] = make_float2(ax, ay);
        if (lane == 0) deg[n] = gc;
    }
}

// ---------------------------------------------------------------------------
// GEMM2: out[64-node tile][64-col tile] = agg @ W2 + deg*b2.
// ---------------------------------------------------------------------------
__global__ __launch_bounds__(256) void gemm_out(
    const float* __restrict__ agg, const int* __restrict__ deg,
    const float* __restrict__ W2, const float* __restrict__ b2,
    float* __restrict__ out)
{
    __shared__ float As[HIDDEN][68];
    __shared__ float Bs[HIDDEN][68];

    const int node0 = blockIdx.x * 64;
    const int col0t = blockIdx.y * 64;
    const int tid   = threadIdx.x;

    for (int idx = tid; idx < 64 * HIDDEN; idx += 256) {
        int m = idx & 63;
        int k = idx >> 6;
        int n = node0 + m;
        As[k][m] = (n < N_NODES) ? agg[(size_t)n * HIDDEN + k] : 0.f;
    }
    for (int idx = tid; idx < 64 * HIDDEN; idx += 256) {
        int n = idx & 63;
        int k = idx >> 6;
        Bs[k][n] = W2[k * OUT_DIM + col0t + n];
    }
    __syncthreads();

    const int tx = tid & 15, ty = tid >> 4;
    const int m0 = ty * 4, n0 = tx * 4;
    float acc[4][4] = {};

    #pragma unroll 4
    for (int k = 0; k < HIDDEN; ++k) {
        float4 av = *(const float4*)&As[k][m0];
        float4 bv = *(const float4*)&Bs[k][n0];
        float aa[4] = {av.x, av.y, av.z, av.w};
        float bb[4] = {bv.x, bv.y, bv.z, bv.w};
        #pragma unroll
        for (int i = 0; i < 4; ++i)
            #pragma unroll
            for (int j = 0; j < 4; ++j)
                acc[i][j] = fmaf(aa[i], bb[j], acc[i][j]);
    }

    const int colbase = col0t + n0;
    const float4 b2v = *(const float4*)&b2[colbase];
    #pragma unroll
    for (int i = 0; i < 4; ++i) {
        int n = node0 + m0 + i;
        if (n >= N_NODES) continue;
        float dg = (float)deg[n];
        float4 o = make_float4(acc[i][0] + b2v.x * dg, acc[i][1] + b2v.y * dg,
                               acc[i][2] + b2v.z * dg, acc[i][3] + b2v.w * dg);
        *(float4*)&out[(size_t)n * OUT_DIM + colbase] = o;
    }
}

// ---------------------------------------------------------------------------
extern "C" void kernel_launch(void* const* d_in, const int* in_sizes, int n_in,
                              void* d_out, int out_size, void* d_ws, size_t ws_size,
                              hipStream_t stream)
{
    const float* x       = (const float*)d_in[0];
    const float* scalars = (const float*)d_in[1];
    const int*   batch   = (const int*)d_in[2];
    const int*   ei      = (const int*)d_in[3];
    const float* W1      = (const float*)d_in[4];
    const float* b1      = (const float*)d_in[5];
    const float* W2      = (const float*)d_in[6];
    const float* b2      = (const float*)d_in[7];
    float*       out     = (float*)d_out;

    // ws layout: UV | agg | deg | tails | glist | Wf   (~85 MB)
    float*    UV    = (float*)d_ws;
    float*    agg   = UV + (size_t)N_NODES * UV_DIM;
    int*      deg   = (int*)(agg + (size_t)N_NODES * HIDDEN);
    int*      tails = deg + N_NODES;
    unsigned* glist = (unsigned*)(tails + NSLICE);
    float*    Wf    = (float*)(glist + (size_t)NSLICE * CAP);

    hipMemsetAsync(tails, 0, NSLICE * sizeof(int), stream);

    wf_prep<<<(H_DIM * UV_DIM + 255) / 256, 256, 0, stream>>>(W1, Wf);

    gemm_uv<<<dim3((N_NODES + 63) / 64, UV_DIM / 64), 256, 0, stream>>>(
        x, scalars, batch, Wf, b1, UV);

    bin_kernel<<<(N_EDGES + CHUNK - 1) / CHUNK, 256, 0, stream>>>(
        ei, tails, glist);

    aggregate_slice<<<NSLICE, 256, 0, stream>>>(glist, tails, UV, agg, deg);

    gemm_out<<<dim3((N_NODES + 63) / 64, OUT_DIM / 64), 256, 0, stream>>>(
        agg, deg, W2, b2, out);
}

// Round 5
// 280.463 us; speedup vs baseline: 11.3213x; 1.1851x over previous
//
#include <hip/hip_runtime.h>

#define N_NODES   50000
#define N_EDGES   1600000
#define D_FEAT    64
#define N_SCALARS 4
#define H_DIM     68      // D_FEAT + N_SCALARS
#define HIDDEN    128
#define OUT_DIM   128
#define UV_DIM    256     // gemm_uv logical output: [U | V]

#define SLICE_SH  6                         // 64 nodes per slice
#define SLICE_N   (1 << SLICE_SH)
#define NSLICE    ((N_NODES + SLICE_N - 1) >> SLICE_SH)   // 782
#define CAP       2560                      // per-slice capacity (mean 2048, sd 45)
#define CHUNK     4096                      // edges per bin_kernel block

// fp32 -> bf16 round-to-nearest-even
__device__ __forceinline__ unsigned short f2bf(float f) {
    unsigned u = __float_as_uint(f);
    unsigned r = (u + 0x7FFFu + ((u >> 16) & 1u)) >> 16;
    return (unsigned short)r;
}

// ---------------------------------------------------------------------------
// Wf[k][j] = (j<128) ? W1[k][j] - W1[k+68][j] : W1[k+68][j-128]
// ---------------------------------------------------------------------------
__global__ __launch_bounds__(256) void wf_prep(const float* __restrict__ W1,
                                               float* __restrict__ Wf)
{
    int idx = blockIdx.x * 256 + threadIdx.x;
    if (idx >= H_DIM * UV_DIM) return;
    int k = idx >> 8;
    int j = idx & 255;
    float wb = W1[(k + H_DIM) * HIDDEN + (j & 127)];
    Wf[idx] = (j < HIDDEN) ? (W1[k * HIDDEN + j] - wb) : wb;
}

// ---------------------------------------------------------------------------
// GEMM1: [U | V] = h @ Wf.  U (+b1) -> Uf fp32;  V -> Vh bf16.
// ---------------------------------------------------------------------------
__global__ __launch_bounds__(256) void gemm_uv(
    const float* __restrict__ x, const float* __restrict__ scalars,
    const int* __restrict__ batch, const float* __restrict__ Wf,
    const float* __restrict__ b1, float* __restrict__ Uf,
    unsigned short* __restrict__ Vh)
{
    __shared__ float As[H_DIM][68];
    __shared__ float Bs[H_DIM][68];

    const int node0 = blockIdx.x * 64;
    const int col0t = blockIdx.y * 64;
    const int tid   = threadIdx.x;

    for (int idx = tid; idx < 64 * H_DIM; idx += 256) {
        int m = idx & 63;
        int k = idx >> 6;
        int n = node0 + m;
        float v = 0.f;
        if (n < N_NODES)
            v = (k < D_FEAT) ? x[(size_t)n * D_FEAT + k]
                             : scalars[batch[n] * N_SCALARS + (k - D_FEAT)];
        As[k][m] = v;
    }
    for (int idx = tid; idx < 64 * H_DIM; idx += 256) {
        int n = idx & 63;
        int k = idx >> 6;
        Bs[k][n] = Wf[k * UV_DIM + col0t + n];
    }
    __syncthreads();

    const int tx = tid & 15, ty = tid >> 4;
    const int m0 = ty * 4, n0 = tx * 4;
    float acc[4][4] = {};

    #pragma unroll 4
    for (int k = 0; k < H_DIM; ++k) {
        float4 av = *(const float4*)&As[k][m0];
        float4 bv = *(const float4*)&Bs[k][n0];
        float aa[4] = {av.x, av.y, av.z, av.w};
        float bb[4] = {bv.x, bv.y, bv.z, bv.w};
        #pragma unroll
        for (int i = 0; i < 4; ++i)
            #pragma unroll
            for (int j = 0; j < 4; ++j)
                acc[i][j] = fmaf(aa[i], bb[j], acc[i][j]);
    }

    const int colbase = col0t + n0;
    if (colbase < HIDDEN) {
        const float4 bias = *(const float4*)&b1[colbase];
        #pragma unroll
        for (int i = 0; i < 4; ++i) {
            int n = node0 + m0 + i;
            if (n >= N_NODES) continue;
            float4 o = make_float4(acc[i][0] + bias.x, acc[i][1] + bias.y,
                                   acc[i][2] + bias.z, acc[i][3] + bias.w);
            *(float4*)&Uf[(size_t)n * HIDDEN + colbase] = o;
        }
    } else {
        const int vcol = colbase - HIDDEN;
        #pragma unroll
        for (int i = 0; i < 4; ++i) {
            int n = node0 + m0 + i;
            if (n >= N_NODES) continue;
            ushort4 h;
            h.x = f2bf(acc[i][0]); h.y = f2bf(acc[i][1]);
            h.z = f2bf(acc[i][2]); h.w = f2bf(acc[i][3]);
            *(ushort4*)&Vh[(size_t)n * HIDDEN + vcol] = h;
        }
    }
}

// ---------------------------------------------------------------------------
// bin_kernel: per-block LDS counting sort by slice (dst>>6), then append each
// slice's run to glist[slice*CAP ...] via one global atomicAdd per slice.
// Entries packed (dst<<16)|src (both < 65536).
// ---------------------------------------------------------------------------
__global__ __launch_bounds__(256) void bin_kernel(
    const int* __restrict__ ei, int* __restrict__ tails,
    unsigned* __restrict__ glist)
{
    __shared__ unsigned buf[CHUNK];       // 16 KB
    __shared__ int hist[NSLICE];
    __shared__ int binStart[NSLICE];
    __shared__ int cursor[NSLICE];
    __shared__ int gbase[NSLICE];
    __shared__ int scanTmp[256];

    const int tid = threadIdx.x;
    const int e0  = blockIdx.x * CHUNK;
    const int nE  = min(CHUNK, N_EDGES - e0);

    for (int i = tid; i < NSLICE; i += 256) hist[i] = 0;
    __syncthreads();

    unsigned ent[CHUNK / 256];
    #pragma unroll
    for (int j = 0; j < CHUNK / 256; ++j) {
        int e = e0 + tid + j * 256;
        if (e < N_EDGES) {
            unsigned s = (unsigned)ei[e];
            unsigned d = (unsigned)ei[N_EDGES + e];
            ent[j] = (d << 16) | s;
            atomicAdd(&hist[d >> SLICE_SH], 1);
        } else {
            ent[j] = 0xFFFFFFFFu;
        }
    }
    __syncthreads();

    // exclusive scan of hist (256 threads x 4 bins)
    const int base4 = tid * 4;
    int loc[4];
    int sum = 0;
    #pragma unroll
    for (int k = 0; k < 4; ++k) {
        int b = base4 + k;
        loc[k] = (b < NSLICE) ? hist[b] : 0;
        sum += loc[k];
    }
    scanTmp[tid] = sum;
    __syncthreads();
    for (int d = 1; d < 256; d <<= 1) {
        int v = (tid >= d) ? scanTmp[tid - d] : 0;
        __syncthreads();
        scanTmp[tid] += v;
        __syncthreads();
    }
    int run = (tid == 0) ? 0 : scanTmp[tid - 1];
    #pragma unroll
    for (int k = 0; k < 4; ++k) {
        int b = base4 + k;
        if (b < NSLICE) { binStart[b] = run; cursor[b] = run; run += loc[k]; }
    }
    __syncthreads();

    #pragma unroll
    for (int j = 0; j < CHUNK / 256; ++j) {
        if (ent[j] != 0xFFFFFFFFu) {
            int sl = (int)(ent[j] >> (16 + SLICE_SH));
            int pos = atomicAdd(&cursor[sl], 1);
            buf[pos] = ent[j];
        }
    }
    __syncthreads();

    for (int s = tid; s < NSLICE; s += 256) {
        int c = hist[s];
        if (c > 0) gbase[s] = atomicAdd(&tails[s], c);
    }
    __syncthreads();

    for (int i = tid; i < nE; i += 256) {
        unsigned e = buf[i];
        int sl = (int)(e >> (16 + SLICE_SH));
        int di = gbase[sl] + (i - binStart[sl]);
        if (di < CAP) glist[(size_t)sl * CAP + di] = e;
    }
}

// ---------------------------------------------------------------------------
// aggregate_slice: blockIdx.x = slice, blockIdx.y splits nodes 2-way.
// LDS counting sort by dst&63, then waves accumulate relu(U[n]+V[src])
// in registers; V rows are bf16 (4 B per lane per edge).
// ---------------------------------------------------------------------------
__global__ __launch_bounds__(256) void aggregate_slice(
    const unsigned* __restrict__ glist, const int* __restrict__ tails,
    const float* __restrict__ Uf, const unsigned short* __restrict__ Vh,
    float* __restrict__ agg, int* __restrict__ deg)
{
    __shared__ int h64[64];
    __shared__ int start64[64];
    __shared__ int cur64[64];
    __shared__ int scanB[64];
    __shared__ unsigned sbuf[CAP];

    const int slice = blockIdx.x;
    const int node0 = slice << SLICE_SH;
    const int tid   = threadIdx.x;
    const unsigned* lst = glist + (size_t)slice * CAP;
    const int cnt = min(tails[slice], CAP);

    if (tid < 64) h64[tid] = 0;
    __syncthreads();
    for (int i = tid; i < cnt; i += 256)
        atomicAdd(&h64[(lst[i] >> 16) & 63], 1);
    __syncthreads();
    if (tid < 64) scanB[tid] = h64[tid];
    __syncthreads();
    for (int d = 1; d < 64; d <<= 1) {
        int v = 0;
        if (tid < 64 && tid >= d) v = scanB[tid - d];
        __syncthreads();
        if (tid < 64) scanB[tid] += v;
        __syncthreads();
    }
    if (tid < 64) {
        start64[tid] = scanB[tid] - h64[tid];
        cur64[tid]   = scanB[tid] - h64[tid];
    }
    __syncthreads();
    for (int i = tid; i < cnt; i += 256) {
        unsigned e = lst[i];
        int dl = (e >> 16) & 63;
        int p = atomicAdd(&cur64[dl], 1);
        sbuf[p] = e & 0xFFFFu;
    }
    __syncthreads();

    const int wave = tid >> 6;
    const int lane = tid & 63;
    const int c2   = lane * 2;

    // this block owns nodes dl = (wave + 4*blockIdx.y), step 8
    for (int dl = wave + 4 * blockIdx.y; dl < 64; dl += 8) {
        int n = node0 + dl;
        if (n >= N_NODES) continue;
        const int gb = start64[dl];
        const int gc = h64[dl];
        const float2 u = *(const float2*)&Uf[(size_t)n * HIDDEN + c2];
        float ax = 0.f, ay = 0.f;

        int p = gb, pe = gb + gc;
        for (; p + 4 <= pe; p += 4) {
            int s0 = sbuf[p + 0];
            int s1 = sbuf[p + 1];
            int s2 = sbuf[p + 2];
            int s3 = sbuf[p + 3];
            unsigned w0 = *(const unsigned*)&Vh[(size_t)s0 * HIDDEN + c2];
            unsigned w1 = *(const unsigned*)&Vh[(size_t)s1 * HIDDEN + c2];
            unsigned w2 = *(const unsigned*)&Vh[(size_t)s2 * HIDDEN + c2];
            unsigned w3 = *(const unsigned*)&Vh[(size_t)s3 * HIDDEN + c2];
            ax += fmaxf(u.x + __uint_as_float(w0 << 16), 0.f)
                + fmaxf(u.x + __uint_as_float(w1 << 16), 0.f)
                + fmaxf(u.x + __uint_as_float(w2 << 16), 0.f)
                + fmaxf(u.x + __uint_as_float(w3 << 16), 0.f);
            ay += fmaxf(u.y + __uint_as_float(w0 & 0xFFFF0000u), 0.f)
                + fmaxf(u.y + __uint_as_float(w1 & 0xFFFF0000u), 0.f)
                + fmaxf(u.y + __uint_as_float(w2 & 0xFFFF0000u), 0.f)
                + fmaxf(u.y + __uint_as_float(w3 & 0xFFFF0000u), 0.f);
        }
        for (; p < pe; ++p) {
            int s0 = sbuf[p];
            unsigned w0 = *(const unsigned*)&Vh[(size_t)s0 * HIDDEN + c2];
            ax += fmaxf(u.x + __uint_as_float(w0 << 16), 0.f);
            ay += fmaxf(u.y + __uint_as_float(w0 & 0xFFFF0000u), 0.f);
        }
        *(float2*)&agg[(size_t)n * HIDDEN + c2] = make_float2(ax, ay);
        if (lane == 0) deg[n] = gc;
    }
}

// ---------------------------------------------------------------------------
// GEMM2: out = agg @ W2 + deg*b2.
// ---------------------------------------------------------------------------
__global__ __launch_bounds__(256) void gemm_out(
    const float* __restrict__ agg, const int* __restrict__ deg,
    const float* __restrict__ W2, const float* __restrict__ b2,
    float* __restrict__ out)
{
    __shared__ float As[HIDDEN][68];
    __shared__ float Bs[HIDDEN][68];

    const int node0 = blockIdx.x * 64;
    const int col0t = blockIdx.y * 64;
    const int tid   = threadIdx.x;

    for (int idx = tid; idx < 64 * HIDDEN; idx += 256) {
        int m = idx & 63;
        int k = idx >> 6;
        int n = node0 + m;
        As[k][m] = (n < N_NODES) ? agg[(size_t)n * HIDDEN + k] : 0.f;
    }
    for (int idx = tid; idx < 64 * HIDDEN; idx += 256) {
        int n = idx & 63;
        int k = idx >> 6;
        Bs[k][n] = W2[k * OUT_DIM + col0t + n];
    }
    __syncthreads();

    const int tx = tid & 15, ty = tid >> 4;
    const int m0 = ty * 4, n0 = tx * 4;
    float acc[4][4] = {};

    #pragma unroll 4
    for (int k = 0; k < HIDDEN; ++k) {
        float4 av = *(const float4*)&As[k][m0];
        float4 bv = *(const float4*)&Bs[k][n0];
        float aa[4] = {av.x, av.y, av.z, av.w};
        float bb[4] = {bv.x, bv.y, bv.z, bv.w};
        #pragma unroll
        for (int i = 0; i < 4; ++i)
            #pragma unroll
            for (int j = 0; j < 4; ++j)
                acc[i][j] = fmaf(aa[i], bb[j], acc[i][j]);
    }

    const int colbase = col0t + n0;
    const float4 b2v = *(const float4*)&b2[colbase];
    #pragma unroll
    for (int i = 0; i < 4; ++i) {
        int n = node0 + m0 + i;
        if (n >= N_NODES) continue;
        float dg = (float)deg[n];
        float4 o = make_float4(acc[i][0] + b2v.x * dg, acc[i][1] + b2v.y * dg,
                               acc[i][2] + b2v.z * dg, acc[i][3] + b2v.w * dg);
        *(float4*)&out[(size_t)n * OUT_DIM + colbase] = o;
    }
}

// ---------------------------------------------------------------------------
extern "C" void kernel_launch(void* const* d_in, const int* in_sizes, int n_in,
                              void* d_out, int out_size, void* d_ws, size_t ws_size,
                              hipStream_t stream)
{
    const float* x       = (const float*)d_in[0];
    const float* scalars = (const float*)d_in[1];
    const int*   batch   = (const int*)d_in[2];
    const int*   ei      = (const int*)d_in[3];
    const float* W1      = (const float*)d_in[4];
    const float* b1      = (const float*)d_in[5];
    const float* W2      = (const float*)d_in[6];
    const float* b2      = (const float*)d_in[7];
    float*       out     = (float*)d_out;

    // ws layout: Uf | agg | Vh | glist | deg | tails | Wf   (~73 MB)
    float*          Uf    = (float*)d_ws;
    float*          agg   = Uf + (size_t)N_NODES * HIDDEN;
    unsigned short* Vh    = (unsigned short*)(agg + (size_t)N_NODES * HIDDEN);
    unsigned*       glist = (unsigned*)(Vh + (size_t)N_NODES * HIDDEN);
    int*            deg   = (int*)(glist + (size_t)NSLICE * CAP);
    int*            tails = deg + N_NODES;
    float*          Wf    = (float*)(tails + NSLICE);

    hipMemsetAsync(tails, 0, NSLICE * sizeof(int), stream);

    wf_prep<<<(H_DIM * UV_DIM + 255) / 256, 256, 0, stream>>>(W1, Wf);

    gemm_uv<<<dim3((N_NODES + 63) / 64, UV_DIM / 64), 256, 0, stream>>>(
        x, scalars, batch, Wf, b1, Uf, Vh);

    bin_kernel<<<(N_EDGES + CHUNK - 1) / CHUNK, 256, 0, stream>>>(
        ei, tails, glist);

    aggregate_slice<<<dim3(NSLICE, 2), 256, 0, stream>>>(
        glist, tails, Uf, Vh, agg, deg);

    gemm_out<<<dim3((N_NODES + 63) / 64, OUT_DIM / 64), 256, 0, stream>>>(
        agg, deg, W2, b2, out);
}

// Round 6
// 229.262 us; speedup vs baseline: 13.8497x; 1.2233x over previous
//
#include <hip/hip_runtime.h>

#define N_NODES   50000
#define N_EDGES   1600000
#define D_FEAT    64
#define N_SCALARS 4
#define HIDDEN    128
#define OUT_DIM   128
#define N_GRAPHS  64
#define UV_DIM    256

#define SLICE_SH  6
#define SLICE_N   (1 << SLICE_SH)
#define NSLICE    ((N_NODES + SLICE_N - 1) >> SLICE_SH)   // 782
#define CAP       2560
#define CHUNK     4096

#define N_WAVES   (N_NODES / 16)        // 3125 row-waves (50000 = 3125*16 exact)

typedef __attribute__((ext_vector_type(8))) short  short8;   // 8 bf16 (4 VGPRs)
typedef __attribute__((ext_vector_type(4))) float  f32x4;    // MFMA acc

// fp32 -> bf16 round-to-nearest-even (bit pattern)
__device__ __forceinline__ unsigned short f2bf(float f) {
    unsigned u = __float_as_uint(f);
    unsigned r = (u + 0x7FFFu + ((u >> 16) & 1u)) >> 16;
    return (unsigned short)r;
}

// Wf[k][j] = (j<128) ? W1[k][j] - W1[k+68][j] : W1[k+68][j-128]   (k<68)
__device__ __forceinline__ float wf_elem(const float* W1, int k, int j) {
    float wb = W1[(k + 68) * HIDDEN + (j & 127)];
    return (j < HIDDEN) ? (W1[k * HIDDEN + j] - wb) : wb;
}

// ---------------------------------------------------------------------------
// prep: WfT bf16 [256][64] (x-part of Wf, transposed)
//       W2T bf16 [128][128] (W2 transposed)
//       SG  fp32 [64][256]  = scalars @ Wf_s  (+ b1 on U half)
// ---------------------------------------------------------------------------
__global__ __launch_bounds__(256) void prep_kernel(
    const float* __restrict__ W1, const float* __restrict__ b1,
    const float* __restrict__ W2, const float* __restrict__ scalars,
    unsigned short* __restrict__ WfT, unsigned short* __restrict__ W2T,
    float* __restrict__ SG)
{
    const int idx = blockIdx.x * 256 + threadIdx.x;   // 0..16383
    {   // WfT[j][k], j<256, k<64
        int j = idx >> 6, k = idx & 63;
        WfT[idx] = f2bf(wf_elem(W1, k, j));
    }
    {   // W2T[j][k], j<128, k<128
        int j = idx >> 7, k = idx & 127;
        W2T[idx] = f2bf(W2[k * OUT_DIM + j]);
    }
    {   // SG[g][j]
        int g = idx >> 8, j = idx & 255;
        float s = (j < HIDDEN) ? b1[j] : 0.f;
        #pragma unroll
        for (int t = 0; t < N_SCALARS; ++t)
            s = fmaf(scalars[g * N_SCALARS + t], wf_elem(W1, D_FEAT + t, j), s);
        SG[idx] = s;
    }
}

// ---------------------------------------------------------------------------
// GEMM1 (MFMA): [Uf | Vh] = x @ WfT^T + SG[batch[n]]
// One wave = 16 rows x 256 cols; K=64 = 2 MFMA k-steps; no LDS.
// ---------------------------------------------------------------------------
__global__ __launch_bounds__(256) void gemm1_mfma(
    const float* __restrict__ x, const int* __restrict__ batch,
    const unsigned short* __restrict__ WfT, const float* __restrict__ SG,
    float* __restrict__ Uf, unsigned short* __restrict__ Vh)
{
    const int wid = (blockIdx.x * 256 + threadIdx.x) >> 6;
    if (wid >= N_WAVES) return;
    const int lane = threadIdx.x & 63;
    const int quad = lane >> 4;
    const int l15  = lane & 15;
    const int row0 = wid * 16;

    f32x4 acc[16];
    #pragma unroll
    for (int c = 0; c < 16; ++c) { f32x4 z = {0.f, 0.f, 0.f, 0.f}; acc[c] = z; }

    const float* xrow = x + (size_t)(row0 + l15) * D_FEAT;
    #pragma unroll
    for (int t = 0; t < 2; ++t) {
        const int k0 = 32 * t + quad * 8;
        float4 a0 = *(const float4*)(xrow + k0);
        float4 a1 = *(const float4*)(xrow + k0 + 4);
        short8 af;
        af[0] = (short)f2bf(a0.x); af[1] = (short)f2bf(a0.y);
        af[2] = (short)f2bf(a0.z); af[3] = (short)f2bf(a0.w);
        af[4] = (short)f2bf(a1.x); af[5] = (short)f2bf(a1.y);
        af[6] = (short)f2bf(a1.z); af[7] = (short)f2bf(a1.w);
        #pragma unroll
        for (int c = 0; c < 16; ++c) {
            short8 bf = *(const short8*)(WfT + (size_t)(c * 16 + l15) * 64 + k0);
            acc[c] = __builtin_amdgcn_mfma_f32_16x16x32_bf16(af, bf, acc[c], 0, 0, 0);
        }
    }

    int bg[4];
    #pragma unroll
    for (int j = 0; j < 4; ++j) bg[j] = batch[row0 + quad * 4 + j];

    #pragma unroll
    for (int c = 0; c < 16; ++c) {
        const int col = c * 16 + l15;
        #pragma unroll
        for (int j = 0; j < 4; ++j) {
            const int n = row0 + quad * 4 + j;
            float v = acc[c][j] + SG[bg[j] * UV_DIM + col];
            if (col < HIDDEN) Uf[(size_t)n * HIDDEN + col] = v;
            else              Vh[(size_t)n * HIDDEN + (col - HIDDEN)] = f2bf(v);
        }
    }
}

// ---------------------------------------------------------------------------
// bin_kernel: per-block LDS counting sort by slice (dst>>6), append runs to
// glist[slice*CAP..] with one global atomicAdd per slice per block.
// ---------------------------------------------------------------------------
__global__ __launch_bounds__(256) void bin_kernel(
    const int* __restrict__ ei, int* __restrict__ tails,
    unsigned* __restrict__ glist)
{
    __shared__ unsigned buf[CHUNK];
    __shared__ int hist[NSLICE];
    __shared__ int binStart[NSLICE];
    __shared__ int cursor[NSLICE];
    __shared__ int gbase[NSLICE];
    __shared__ int scanTmp[256];

    const int tid = threadIdx.x;
    const int e0  = blockIdx.x * CHUNK;
    const int nE  = min(CHUNK, N_EDGES - e0);

    for (int i = tid; i < NSLICE; i += 256) hist[i] = 0;
    __syncthreads();

    unsigned ent[CHUNK / 256];
    #pragma unroll
    for (int j = 0; j < CHUNK / 256; ++j) {
        int e = e0 + tid + j * 256;
        if (e < N_EDGES) {
            unsigned s = (unsigned)ei[e];
            unsigned d = (unsigned)ei[N_EDGES + e];
            ent[j] = (d << 16) | s;
            atomicAdd(&hist[d >> SLICE_SH], 1);
        } else {
            ent[j] = 0xFFFFFFFFu;
        }
    }
    __syncthreads();

    const int base4 = tid * 4;
    int loc[4];
    int sum = 0;
    #pragma unroll
    for (int k = 0; k < 4; ++k) {
        int b = base4 + k;
        loc[k] = (b < NSLICE) ? hist[b] : 0;
        sum += loc[k];
    }
    scanTmp[tid] = sum;
    __syncthreads();
    for (int d = 1; d < 256; d <<= 1) {
        int v = (tid >= d) ? scanTmp[tid - d] : 0;
        __syncthreads();
        scanTmp[tid] += v;
        __syncthreads();
    }
    int run = (tid == 0) ? 0 : scanTmp[tid - 1];
    #pragma unroll
    for (int k = 0; k < 4; ++k) {
        int b = base4 + k;
        if (b < NSLICE) { binStart[b] = run; cursor[b] = run; run += loc[k]; }
    }
    __syncthreads();

    #pragma unroll
    for (int j = 0; j < CHUNK / 256; ++j) {
        if (ent[j] != 0xFFFFFFFFu) {
            int sl = (int)(ent[j] >> (16 + SLICE_SH));
            int pos = atomicAdd(&cursor[sl], 1);
            buf[pos] = ent[j];
        }
    }
    __syncthreads();

    for (int s = tid; s < NSLICE; s += 256) {
        int c = hist[s];
        if (c > 0) gbase[s] = atomicAdd(&tails[s], c);
    }
    __syncthreads();

    for (int i = tid; i < nE; i += 256) {
        unsigned e = buf[i];
        int sl = (int)(e >> (16 + SLICE_SH));
        int di = gbase[sl] + (i - binStart[sl]);
        if (di < CAP) glist[(size_t)sl * CAP + di] = e;
    }
}

// ---------------------------------------------------------------------------
// aggregate_slice: blockIdx.x = slice, blockIdx.y splits nodes 2-way.
// LDS counting sort by dst&63; waves accumulate relu(U[n]+V[src]) in regs.
// Output agg in bf16 (consumed by MFMA GEMM2).
// ---------------------------------------------------------------------------
__global__ __launch_bounds__(256) void aggregate_slice(
    const unsigned* __restrict__ glist, const int* __restrict__ tails,
    const float* __restrict__ Uf, const unsigned short* __restrict__ Vh,
    unsigned short* __restrict__ aggbf, int* __restrict__ deg)
{
    __shared__ int h64[64];
    __shared__ int start64[64];
    __shared__ int cur64[64];
    __shared__ int scanB[64];
    __shared__ unsigned sbuf[CAP];

    const int slice = blockIdx.x;
    const int node0 = slice << SLICE_SH;
    const int tid   = threadIdx.x;
    const unsigned* lst = glist + (size_t)slice * CAP;
    const int cnt = min(tails[slice], CAP);

    if (tid < 64) h64[tid] = 0;
    __syncthreads();
    for (int i = tid; i < cnt; i += 256)
        atomicAdd(&h64[(lst[i] >> 16) & 63], 1);
    __syncthreads();
    if (tid < 64) scanB[tid] = h64[tid];
    __syncthreads();
    for (int d = 1; d < 64; d <<= 1) {
        int v = 0;
        if (tid < 64 && tid >= d) v = scanB[tid - d];
        __syncthreads();
        if (tid < 64) scanB[tid] += v;
        __syncthreads();
    }
    if (tid < 64) {
        start64[tid] = scanB[tid] - h64[tid];
        cur64[tid]   = scanB[tid] - h64[tid];
    }
    __syncthreads();
    for (int i = tid; i < cnt; i += 256) {
        unsigned e = lst[i];
        int dl = (e >> 16) & 63;
        int p = atomicAdd(&cur64[dl], 1);
        sbuf[p] = e & 0xFFFFu;
    }
    __syncthreads();

    const int wave = tid >> 6;
    const int lane = tid & 63;
    const int c2   = lane * 2;

    for (int dl = wave + 4 * blockIdx.y; dl < 64; dl += 8) {
        int n = node0 + dl;
        if (n >= N_NODES) continue;
        const int gb = start64[dl];
        const int gc = h64[dl];
        const float2 u = *(const float2*)&Uf[(size_t)n * HIDDEN + c2];
        float ax = 0.f, ay = 0.f;

        int p = gb, pe = gb + gc;
        for (; p + 4 <= pe; p += 4) {
            int s0 = sbuf[p + 0];
            int s1 = sbuf[p + 1];
            int s2 = sbuf[p + 2];
            int s3 = sbuf[p + 3];
            unsigned w0 = *(const unsigned*)&Vh[(size_t)s0 * HIDDEN + c2];
            unsigned w1 = *(const unsigned*)&Vh[(size_t)s1 * HIDDEN + c2];
            unsigned w2 = *(const unsigned*)&Vh[(size_t)s2 * HIDDEN + c2];
            unsigned w3 = *(const unsigned*)&Vh[(size_t)s3 * HIDDEN + c2];
            ax += fmaxf(u.x + __uint_as_float(w0 << 16), 0.f)
                + fmaxf(u.x + __uint_as_float(w1 << 16), 0.f)
                + fmaxf(u.x + __uint_as_float(w2 << 16), 0.f)
                + fmaxf(u.x + __uint_as_float(w3 << 16), 0.f);
            ay += fmaxf(u.y + __uint_as_float(w0 & 0xFFFF0000u), 0.f)
                + fmaxf(u.y + __uint_as_float(w1 & 0xFFFF0000u), 0.f)
                + fmaxf(u.y + __uint_as_float(w2 & 0xFFFF0000u), 0.f)
                + fmaxf(u.y + __uint_as_float(w3 & 0xFFFF0000u), 0.f);
        }
        for (; p < pe; ++p) {
            int s0 = sbuf[p];
            unsigned w0 = *(const unsigned*)&Vh[(size_t)s0 * HIDDEN + c2];
            ax += fmaxf(u.x + __uint_as_float(w0 << 16), 0.f);
            ay += fmaxf(u.y + __uint_as_float(w0 & 0xFFFF0000u), 0.f);
        }
        unsigned pk = ((unsigned)f2bf(ay) << 16) | (unsigned)f2bf(ax);
        *(unsigned*)&aggbf[(size_t)n * HIDDEN + c2] = pk;
        if (lane == 0) deg[n] = gc;
    }
}

// ---------------------------------------------------------------------------
// GEMM2 (MFMA): out = aggbf @ W2T^T + deg * b2.  K=128 = 4 k-steps; no LDS.
// ---------------------------------------------------------------------------
__global__ __launch_bounds__(256) void gemm2_mfma(
    const unsigned short* __restrict__ aggbf, const int* __restrict__ deg,
    const unsigned short* __restrict__ W2T, const float* __restrict__ b2,
    float* __restrict__ out)
{
    const int wid = (blockIdx.x * 256 + threadIdx.x) >> 6;
    if (wid >= N_WAVES) return;
    const int lane = threadIdx.x & 63;
    const int quad = lane >> 4;
    const int l15  = lane & 15;
    const int row0 = wid * 16;

    f32x4 acc[8];
    #pragma unroll
    for (int c = 0; c < 8; ++c) { f32x4 z = {0.f, 0.f, 0.f, 0.f}; acc[c] = z; }

    const unsigned short* arow = aggbf + (size_t)(row0 + l15) * HIDDEN;
    #pragma unroll
    for (int t = 0; t < 4; ++t) {
        const int k0 = 32 * t + quad * 8;
        short8 af = *(const short8*)(arow + k0);
        #pragma unroll
        for (int c = 0; c < 8; ++c) {
            short8 bf = *(const short8*)(W2T + (size_t)(c * 16 + l15) * HIDDEN + k0);
            acc[c] = __builtin_amdgcn_mfma_f32_16x16x32_bf16(af, bf, acc[c], 0, 0, 0);
        }
    }

    int dg[4];
    #pragma unroll
    for (int j = 0; j < 4; ++j) dg[j] = deg[row0 + quad * 4 + j];

    #pragma unroll
    for (int c = 0; c < 8; ++c) {
        const int col = c * 16 + l15;
        const float bb = b2[col];
        #pragma unroll
        for (int j = 0; j < 4; ++j) {
            const int n = row0 + quad * 4 + j;
            out[(size_t)n * OUT_DIM + col] = acc[c][j] + bb * (float)dg[j];
        }
    }
}

// ---------------------------------------------------------------------------
extern "C" void kernel_launch(void* const* d_in, const int* in_sizes, int n_in,
                              void* d_out, int out_size, void* d_ws, size_t ws_size,
                              hipStream_t stream)
{
    const float* x       = (const float*)d_in[0];
    const float* scalars = (const float*)d_in[1];
    const int*   batch   = (const int*)d_in[2];
    const int*   ei      = (const int*)d_in[3];
    const float* W1      = (const float*)d_in[4];
    const float* b1      = (const float*)d_in[5];
    const float* W2      = (const float*)d_in[6];
    const float* b2      = (const float*)d_in[7];
    float*       out     = (float*)d_out;

    // ws: Uf | aggbf | Vh | glist | WfT | W2T | SG | deg | tails  (~55 MB)
    float*          Uf    = (float*)d_ws;
    unsigned short* aggbf = (unsigned short*)(Uf + (size_t)N_NODES * HIDDEN);
    unsigned short* Vh    = aggbf + (size_t)N_NODES * HIDDEN;
    unsigned*       glist = (unsigned*)(Vh + (size_t)N_NODES * HIDDEN);
    unsigned short* WfT   = (unsigned short*)(glist + (size_t)NSLICE * CAP);
    unsigned short* W2T   = WfT + 256 * 64;
    float*          SG    = (float*)(W2T + 128 * 128);
    int*            deg   = (int*)(SG + 64 * 256);
    int*            tails = deg + N_NODES;

    hipMemsetAsync(tails, 0, NSLICE * sizeof(int), stream);

    prep_kernel<<<64, 256, 0, stream>>>(W1, b1, W2, scalars, WfT, W2T, SG);

    gemm1_mfma<<<(N_WAVES * 64 + 255) / 256, 256, 0, stream>>>(
        x, batch, WfT, SG, Uf, Vh);

    bin_kernel<<<(N_EDGES + CHUNK - 1) / CHUNK, 256, 0, stream>>>(
        ei, tails, glist);

    aggregate_slice<<<dim3(NSLICE, 2), 256, 0, stream>>>(
        glist, tails, Uf, Vh, aggbf, deg);

    gemm2_mfma<<<(N_WAVES * 64 + 255) / 256, 256, 0, stream>>>(
        aggbf, deg, W2T, b2, out);
}

// Round 7
// 207.274 us; speedup vs baseline: 15.3188x; 1.1061x over previous
//
#include <hip/hip_runtime.h>

#define N_NODES   50000
#define N_EDGES   1600000
#define D_FEAT    64
#define N_SCALARS 4
#define HIDDEN    128
#define OUT_DIM   128
#define UV_DIM    256

#define SLICE_SH  6
#define SLICE_N   (1 << SLICE_SH)
#define NSLICE    ((N_NODES + SLICE_N - 1) >> SLICE_SH)   // 782
#define CAP       2560
#define CHUNK     4096

#define N_WAVES   (N_NODES / 16)                  // 3125 (exact)
#define G1_BLOCKS ((N_WAVES + 3) / 4)             // 782 blocks of 4 waves
#define BIN_BLOCKS ((N_EDGES + CHUNK - 1) / CHUNK) // 391

typedef __attribute__((ext_vector_type(8))) _Float16 half8;   // MFMA A/B frag
typedef __attribute__((ext_vector_type(2))) _Float16 half2v;  // packed math
typedef __attribute__((ext_vector_type(4))) float    f32x4;   // MFMA acc

// Wf[k][j] = (j<128) ? W1[k][j] - W1[k+68][j] : W1[k+68][j-128]   (k<68)
__device__ __forceinline__ float wf_elem(const float* W1, int k, int j) {
    float wb = W1[(k + 68) * HIDDEN + (j & 127)];
    return (j < HIDDEN) ? (W1[k * HIDDEN + j] - wb) : wb;
}

// ---------------------------------------------------------------------------
// prep: WfT f16 [256][64], W2T f16 [128][128], SG f32 [64][256], zero tails.
// ---------------------------------------------------------------------------
__global__ __launch_bounds__(256) void prep_kernel(
    const float* __restrict__ W1, const float* __restrict__ b1,
    const float* __restrict__ W2, const float* __restrict__ scalars,
    _Float16* __restrict__ WfT, _Float16* __restrict__ W2T,
    float* __restrict__ SG, int* __restrict__ tails)
{
    const int idx = blockIdx.x * 256 + threadIdx.x;   // 0..16383
    {   int j = idx >> 6, k = idx & 63;
        WfT[idx] = (_Float16)wf_elem(W1, k, j); }
    {   int j = idx >> 7, k = idx & 127;
        W2T[idx] = (_Float16)W2[k * OUT_DIM + j]; }
    {   int g = idx >> 8, j = idx & 255;
        float s = (j < HIDDEN) ? b1[j] : 0.f;
        #pragma unroll
        for (int t = 0; t < N_SCALARS; ++t)
            s = fmaf(scalars[g * N_SCALARS + t], wf_elem(W1, D_FEAT + t, j), s);
        SG[idx] = s; }
    if (idx < NSLICE) tails[idx] = 0;
}

// ---------------------------------------------------------------------------
// Fused kernel: blocks [0, G1_BLOCKS) run GEMM1 (MFMA f16, no LDS);
// blocks [G1_BLOCKS, G1_BLOCKS+BIN_BLOCKS) run edge binning (LDS sort).
// Independent work — fusing overlaps MFMA/store-heavy with LDS/atomic-heavy.
// ---------------------------------------------------------------------------
__global__ __launch_bounds__(256) void gemm1_bin(
    const float* __restrict__ x, const int* __restrict__ batch,
    const _Float16* __restrict__ WfT, const float* __restrict__ SG,
    _Float16* __restrict__ Uh, _Float16* __restrict__ Vh,
    const int* __restrict__ ei, int* __restrict__ tails,
    unsigned* __restrict__ glist)
{
    __shared__ unsigned buf[CHUNK];       // 16 KB (bin path only)
    __shared__ int hist[NSLICE];
    __shared__ int binStart[NSLICE];
    __shared__ int cursor[NSLICE];
    __shared__ int gbase[NSLICE];
    __shared__ int scanTmp[256];

    const int tid = threadIdx.x;

    if (blockIdx.x < G1_BLOCKS) {
        // ----------------- GEMM1: [Uh|Vh] = f16(x) @ WfT^T + SG[batch] ----
        const int wid = (blockIdx.x * 256 + tid) >> 6;
        if (wid >= N_WAVES) return;
        const int lane = tid & 63;
        const int quad = lane >> 4;
        const int l15  = lane & 15;
        const int row0 = wid * 16;

        f32x4 acc[16];
        #pragma unroll
        for (int c = 0; c < 16; ++c) { f32x4 z = {0.f,0.f,0.f,0.f}; acc[c] = z; }

        const float* xrow = x + (row0 + l15) * D_FEAT;
        #pragma unroll
        for (int t = 0; t < 2; ++t) {
            const int k0 = 32 * t + quad * 8;
            float4 a0 = *(const float4*)(xrow + k0);
            float4 a1 = *(const float4*)(xrow + k0 + 4);
            half8 af;
            af[0] = (_Float16)a0.x; af[1] = (_Float16)a0.y;
            af[2] = (_Float16)a0.z; af[3] = (_Float16)a0.w;
            af[4] = (_Float16)a1.x; af[5] = (_Float16)a1.y;
            af[6] = (_Float16)a1.z; af[7] = (_Float16)a1.w;
            #pragma unroll
            for (int c = 0; c < 16; ++c) {
                half8 bf = *(const half8*)(WfT + (c * 16 + l15) * 64 + k0);
                acc[c] = __builtin_amdgcn_mfma_f32_16x16x32_f16(af, bf, acc[c], 0, 0, 0);
            }
        }

        int bg[4];
        #pragma unroll
        for (int j = 0; j < 4; ++j) bg[j] = batch[row0 + quad * 4 + j];

        #pragma unroll
        for (int c = 0; c < 16; ++c) {
            const int col = c * 16 + l15;
            #pragma unroll
            for (int j = 0; j < 4; ++j) {
                const int n = row0 + quad * 4 + j;
                float v = acc[c][j] + SG[bg[j] * UV_DIM + col];
                if (col < HIDDEN) Uh[(n << 7) + col] = (_Float16)v;
                else              Vh[(n << 7) + col - HIDDEN] = (_Float16)v;
            }
        }
        return;
    }

    // ----------------- BIN: LDS counting sort by slice, append to glist ---
    const int e0  = (blockIdx.x - G1_BLOCKS) * CHUNK;
    const int nE  = min(CHUNK, N_EDGES - e0);

    for (int i = tid; i < NSLICE; i += 256) hist[i] = 0;
    __syncthreads();

    unsigned ent[CHUNK / 256];
    #pragma unroll
    for (int j = 0; j < CHUNK / 256; ++j) {
        int e = e0 + tid + j * 256;
        if (e < N_EDGES) {
            unsigned s = (unsigned)ei[e];
            unsigned d = (unsigned)ei[N_EDGES + e];
            ent[j] = (d << 16) | s;
            atomicAdd(&hist[d >> SLICE_SH], 1);
        } else {
            ent[j] = 0xFFFFFFFFu;
        }
    }
    __syncthreads();

    const int base4 = tid * 4;
    int loc[4];
    int sum = 0;
    #pragma unroll
    for (int k = 0; k < 4; ++k) {
        int b = base4 + k;
        loc[k] = (b < NSLICE) ? hist[b] : 0;
        sum += loc[k];
    }
    scanTmp[tid] = sum;
    __syncthreads();
    for (int d = 1; d < 256; d <<= 1) {
        int v = (tid >= d) ? scanTmp[tid - d] : 0;
        __syncthreads();
        scanTmp[tid] += v;
        __syncthreads();
    }
    int run = (tid == 0) ? 0 : scanTmp[tid - 1];
    #pragma unroll
    for (int k = 0; k < 4; ++k) {
        int b = base4 + k;
        if (b < NSLICE) { binStart[b] = run; cursor[b] = run; run += loc[k]; }
    }
    __syncthreads();

    #pragma unroll
    for (int j = 0; j < CHUNK / 256; ++j) {
        if (ent[j] != 0xFFFFFFFFu) {
            int sl = (int)(ent[j] >> (16 + SLICE_SH));
            int pos = atomicAdd(&cursor[sl], 1);
            buf[pos] = ent[j];
        }
    }
    __syncthreads();

    for (int s = tid; s < NSLICE; s += 256) {
        int c = hist[s];
        if (c > 0) gbase[s] = atomicAdd(&tails[s], c);
    }
    __syncthreads();

    for (int i = tid; i < nE; i += 256) {
        unsigned e = buf[i];
        int sl = (int)(e >> (16 + SLICE_SH));
        int di = gbase[sl] + (i - binStart[sl]);
        if (di < CAP) glist[(size_t)sl * CAP + di] = e;
    }
}

// ---------------------------------------------------------------------------
// aggregate_slice: blockIdx.x = slice, blockIdx.y splits nodes 2-way.
// LDS counting sort by dst&63; waves accumulate relu(U+V) with packed f16.
// ---------------------------------------------------------------------------
__global__ __launch_bounds__(256) void aggregate_slice(
    const unsigned* __restrict__ glist, const int* __restrict__ tails,
    const _Float16* __restrict__ Uh, const _Float16* __restrict__ Vh,
    _Float16* __restrict__ aggh, int* __restrict__ deg)
{
    __shared__ int h64[64];
    __shared__ int start64[64];
    __shared__ int cur64[64];
    __shared__ int scanB[64];
    __shared__ unsigned sbuf[CAP];

    const int slice = blockIdx.x;
    const int node0 = slice << SLICE_SH;
    const int tid   = threadIdx.x;
    const unsigned* lst = glist + (size_t)slice * CAP;
    const int cnt = min(tails[slice], CAP);

    if (tid < 64) h64[tid] = 0;
    __syncthreads();
    for (int i = tid; i < cnt; i += 256)
        atomicAdd(&h64[(lst[i] >> 16) & 63], 1);
    __syncthreads();
    if (tid < 64) scanB[tid] = h64[tid];
    __syncthreads();
    for (int d = 1; d < 64; d <<= 1) {
        int v = 0;
        if (tid < 64 && tid >= d) v = scanB[tid - d];
        __syncthreads();
        if (tid < 64) scanB[tid] += v;
        __syncthreads();
    }
    if (tid < 64) {
        start64[tid] = scanB[tid] - h64[tid];
        cur64[tid]   = scanB[tid] - h64[tid];
    }
    __syncthreads();
    for (int i = tid; i < cnt; i += 256) {
        unsigned e = lst[i];
        int dl = (e >> 16) & 63;
        int p = atomicAdd(&cur64[dl], 1);
        sbuf[p] = e & 0xFFFFu;
    }
    __syncthreads();

    const int wave = tid >> 6;
    const int lane = tid & 63;
    const int c2   = lane * 2;
    const half2v zero = {(_Float16)0, (_Float16)0};

    for (int dl = wave + 4 * blockIdx.y; dl < 64; dl += 8) {
        int n = node0 + dl;
        if (n >= N_NODES) continue;
        const int gb = start64[dl];
        const int gc = h64[dl];
        const half2v u2 = *(const half2v*)(Uh + (n << 7) + c2);
        half2v acc2 = zero;

        int p = gb, pe = gb + gc;
        for (; p + 8 <= pe; p += 8) {
            int s0 = sbuf[p + 0], s1 = sbuf[p + 1];
            int s2 = sbuf[p + 2], s3 = sbuf[p + 3];
            int s4 = sbuf[p + 4], s5 = sbuf[p + 5];
            int s6 = sbuf[p + 6], s7 = sbuf[p + 7];
            half2v v0 = *(const half2v*)(Vh + (s0 << 7) + c2);
            half2v v1 = *(const half2v*)(Vh + (s1 << 7) + c2);
            half2v v2 = *(const half2v*)(Vh + (s2 << 7) + c2);
            half2v v3 = *(const half2v*)(Vh + (s3 << 7) + c2);
            half2v v4 = *(const half2v*)(Vh + (s4 << 7) + c2);
            half2v v5 = *(const half2v*)(Vh + (s5 << 7) + c2);
            half2v v6 = *(const half2v*)(Vh + (s6 << 7) + c2);
            half2v v7 = *(const half2v*)(Vh + (s7 << 7) + c2);
            half2v m0 = __builtin_elementwise_max(u2 + v0, zero);
            half2v m1 = __builtin_elementwise_max(u2 + v1, zero);
            half2v m2 = __builtin_elementwise_max(u2 + v2, zero);
            half2v m3 = __builtin_elementwise_max(u2 + v3, zero);
            half2v m4 = __builtin_elementwise_max(u2 + v4, zero);
            half2v m5 = __builtin_elementwise_max(u2 + v5, zero);
            half2v m6 = __builtin_elementwise_max(u2 + v6, zero);
            half2v m7 = __builtin_elementwise_max(u2 + v7, zero);
            acc2 += ((m0 + m1) + (m2 + m3)) + ((m4 + m5) + (m6 + m7));
        }
        for (; p < pe; ++p) {
            int s0 = sbuf[p];
            half2v v0 = *(const half2v*)(Vh + (s0 << 7) + c2);
            acc2 += __builtin_elementwise_max(u2 + v0, zero);
        }
        *(half2v*)(aggh + (n << 7) + c2) = acc2;
        if (lane == 0) deg[n] = gc;
    }
}

// ---------------------------------------------------------------------------
// GEMM2 (MFMA f16): out = aggh @ W2T^T + deg * b2.
// ---------------------------------------------------------------------------
__global__ __launch_bounds__(256) void gemm2_mfma(
    const _Float16* __restrict__ aggh, const int* __restrict__ deg,
    const _Float16* __restrict__ W2T, const float* __restrict__ b2,
    float* __restrict__ out)
{
    const int wid = (blockIdx.x * 256 + threadIdx.x) >> 6;
    if (wid >= N_WAVES) return;
    const int lane = threadIdx.x & 63;
    const int quad = lane >> 4;
    const int l15  = lane & 15;
    const int row0 = wid * 16;

    f32x4 acc[8];
    #pragma unroll
    for (int c = 0; c < 8; ++c) { f32x4 z = {0.f,0.f,0.f,0.f}; acc[c] = z; }

    const _Float16* arow = aggh + ((row0 + l15) << 7);
    #pragma unroll
    for (int t = 0; t < 4; ++t) {
        const int k0 = 32 * t + quad * 8;
        half8 af = *(const half8*)(arow + k0);
        #pragma unroll
        for (int c = 0; c < 8; ++c) {
            half8 bf = *(const half8*)(W2T + ((c * 16 + l15) << 7) + k0);
            acc[c] = __builtin_amdgcn_mfma_f32_16x16x32_f16(af, bf, acc[c], 0, 0, 0);
        }
    }

    int dg[4];
    #pragma unroll
    for (int j = 0; j < 4; ++j) dg[j] = deg[row0 + quad * 4 + j];

    #pragma unroll
    for (int c = 0; c < 8; ++c) {
        const int col = c * 16 + l15;
        const float bb = b2[col];
        #pragma unroll
        for (int j = 0; j < 4; ++j) {
            const int n = row0 + quad * 4 + j;
            out[(size_t)n * OUT_DIM + col] = acc[c][j] + bb * (float)dg[j];
        }
    }
}

// ---------------------------------------------------------------------------
extern "C" void kernel_launch(void* const* d_in, const int* in_sizes, int n_in,
                              void* d_out, int out_size, void* d_ws, size_t ws_size,
                              hipStream_t stream)
{
    const float* x       = (const float*)d_in[0];
    const float* scalars = (const float*)d_in[1];
    const int*   batch   = (const int*)d_in[2];
    const int*   ei      = (const int*)d_in[3];
    const float* W1      = (const float*)d_in[4];
    const float* b1      = (const float*)d_in[5];
    const float* W2      = (const float*)d_in[6];
    const float* b2      = (const float*)d_in[7];
    float*       out     = (float*)d_out;

    // ws: Uh | Vh | aggh | glist | WfT | W2T | SG | deg | tails  (~47 MB)
    _Float16* Uh    = (_Float16*)d_ws;
    _Float16* Vh    = Uh + (size_t)N_NODES * HIDDEN;
    _Float16* aggh  = Vh + (size_t)N_NODES * HIDDEN;
    unsigned* glist = (unsigned*)(aggh + (size_t)N_NODES * HIDDEN);
    _Float16* WfT   = (_Float16*)(glist + (size_t)NSLICE * CAP);
    _Float16* W2T   = WfT + 256 * 64;
    float*    SG    = (float*)(W2T + 128 * 128);
    int*      deg   = (int*)(SG + 64 * UV_DIM);
    int*      tails = deg + N_NODES;

    prep_kernel<<<64, 256, 0, stream>>>(W1, b1, W2, scalars, WfT, W2T, SG, tails);

    gemm1_bin<<<G1_BLOCKS + BIN_BLOCKS, 256, 0, stream>>>(
        x, batch, WfT, SG, Uh, Vh, ei, tails, glist);

    aggregate_slice<<<dim3(NSLICE, 2), 256, 0, stream>>>(
        glist, tails, Uh, Vh, aggh, deg);

    gemm2_mfma<<<(N_WAVES * 64 + 255) / 256, 256, 0, stream>>>(
        aggh, deg, W2T, b2, out);
}

// Round 8
// 196.867 us; speedup vs baseline: 16.1286x; 1.0529x over previous
//
#include <hip/hip_runtime.h>

#define N_NODES   50000
#define N_EDGES   1600000
#define D_FEAT    64
#define N_SCALARS 4
#define HIDDEN    128
#define OUT_DIM   128
#define UV_DIM    256

#define SLICE_SH  6
#define SLICE_N   (1 << SLICE_SH)
#define NSLICE    ((N_NODES + SLICE_N - 1) >> SLICE_SH)   // 782
#define CAP       2560
#define CAPQ      1024                    // per-quarter-slice (mean 512 + pad)
#define CHUNK     4096

#define N_WAVES   (N_NODES / 16)                  // 3125 (exact)
#define G1_BLOCKS ((N_WAVES + 3) / 4)             // 782
#define BIN_BLOCKS ((N_EDGES + CHUNK - 1) / CHUNK) // 391

typedef __attribute__((ext_vector_type(8))) _Float16 half8;
typedef __attribute__((ext_vector_type(2))) _Float16 half2v;
typedef __attribute__((ext_vector_type(4))) float    f32x4;

// Wf[k][j] = (j<128) ? W1[k][j] - W1[k+68][j] : W1[k+68][j-128]   (k<68)
__device__ __forceinline__ float wf_elem(const float* W1, int k, int j) {
    float wb = W1[(k + 68) * HIDDEN + (j & 127)];
    return (j < HIDDEN) ? (W1[k * HIDDEN + j] - wb) : wb;
}

// ---------------------------------------------------------------------------
// prep: WfT f16 [256][64], W2T f16 [128][128], SG f32 [64][256], zero tails.
// ---------------------------------------------------------------------------
__global__ __launch_bounds__(256) void prep_kernel(
    const float* __restrict__ W1, const float* __restrict__ b1,
    const float* __restrict__ W2, const float* __restrict__ scalars,
    _Float16* __restrict__ WfT, _Float16* __restrict__ W2T,
    float* __restrict__ SG, int* __restrict__ tails)
{
    const int idx = blockIdx.x * 256 + threadIdx.x;   // 0..16383
    {   int j = idx >> 6, k = idx & 63;
        WfT[idx] = (_Float16)wf_elem(W1, k, j); }
    {   int j = idx >> 7, k = idx & 127;
        W2T[idx] = (_Float16)W2[k * OUT_DIM + j]; }
    {   int g = idx >> 8, j = idx & 255;
        float s = (j < HIDDEN) ? b1[j] : 0.f;
        #pragma unroll
        for (int t = 0; t < N_SCALARS; ++t)
            s = fmaf(scalars[g * N_SCALARS + t], wf_elem(W1, D_FEAT + t, j), s);
        SG[idx] = s; }
    if (idx < NSLICE) tails[idx] = 0;
}

// ---------------------------------------------------------------------------
// Fused: blocks [0,G1_BLOCKS) = GEMM1 (MFMA f16, no LDS);
//        blocks [G1_BLOCKS,...) = edge binning by slice (LDS sort).
// ---------------------------------------------------------------------------
__global__ __launch_bounds__(256) void gemm1_bin(
    const float* __restrict__ x, const int* __restrict__ batch,
    const _Float16* __restrict__ WfT, const float* __restrict__ SG,
    _Float16* __restrict__ Uh, _Float16* __restrict__ Vh,
    const int* __restrict__ ei, int* __restrict__ tails,
    unsigned* __restrict__ glist)
{
    __shared__ unsigned buf[CHUNK];
    __shared__ int hist[NSLICE];
    __shared__ int binStart[NSLICE];
    __shared__ int cursor[NSLICE];
    __shared__ int gbase[NSLICE];
    __shared__ int scanTmp[256];

    const int tid = threadIdx.x;

    if (blockIdx.x < G1_BLOCKS) {
        const int wid = (blockIdx.x * 256 + tid) >> 6;
        if (wid >= N_WAVES) return;
        const int lane = tid & 63;
        const int quad = lane >> 4;
        const int l15  = lane & 15;
        const int row0 = wid * 16;

        f32x4 acc[16];
        #pragma unroll
        for (int c = 0; c < 16; ++c) { f32x4 z = {0.f,0.f,0.f,0.f}; acc[c] = z; }

        const float* xrow = x + (row0 + l15) * D_FEAT;
        #pragma unroll
        for (int t = 0; t < 2; ++t) {
            const int k0 = 32 * t + quad * 8;
            float4 a0 = *(const float4*)(xrow + k0);
            float4 a1 = *(const float4*)(xrow + k0 + 4);
            half8 af;
            af[0] = (_Float16)a0.x; af[1] = (_Float16)a0.y;
            af[2] = (_Float16)a0.z; af[3] = (_Float16)a0.w;
            af[4] = (_Float16)a1.x; af[5] = (_Float16)a1.y;
            af[6] = (_Float16)a1.z; af[7] = (_Float16)a1.w;
            #pragma unroll
            for (int c = 0; c < 16; ++c) {
                half8 bf = *(const half8*)(WfT + (c * 16 + l15) * 64 + k0);
                acc[c] = __builtin_amdgcn_mfma_f32_16x16x32_f16(af, bf, acc[c], 0, 0, 0);
            }
        }

        int bg[4];
        #pragma unroll
        for (int j = 0; j < 4; ++j) bg[j] = batch[row0 + quad * 4 + j];

        #pragma unroll
        for (int c = 0; c < 16; ++c) {
            const int col = c * 16 + l15;
            #pragma unroll
            for (int j = 0; j < 4; ++j) {
                const int n = row0 + quad * 4 + j;
                float v = acc[c][j] + SG[bg[j] * UV_DIM + col];
                if (col < HIDDEN) Uh[(n << 7) + col] = (_Float16)v;
                else              Vh[(n << 7) + col - HIDDEN] = (_Float16)v;
            }
        }
        return;
    }

    const int e0  = (blockIdx.x - G1_BLOCKS) * CHUNK;
    const int nE  = min(CHUNK, N_EDGES - e0);

    for (int i = tid; i < NSLICE; i += 256) hist[i] = 0;
    __syncthreads();

    unsigned ent[CHUNK / 256];
    #pragma unroll
    for (int j = 0; j < CHUNK / 256; ++j) {
        int e = e0 + tid + j * 256;
        if (e < N_EDGES) {
            unsigned s = (unsigned)ei[e];
            unsigned d = (unsigned)ei[N_EDGES + e];
            ent[j] = (d << 16) | s;
            atomicAdd(&hist[d >> SLICE_SH], 1);
        } else {
            ent[j] = 0xFFFFFFFFu;
        }
    }
    __syncthreads();

    const int base4 = tid * 4;
    int loc[4];
    int sum = 0;
    #pragma unroll
    for (int k = 0; k < 4; ++k) {
        int b = base4 + k;
        loc[k] = (b < NSLICE) ? hist[b] : 0;
        sum += loc[k];
    }
    scanTmp[tid] = sum;
    __syncthreads();
    for (int d = 1; d < 256; d <<= 1) {
        int v = (tid >= d) ? scanTmp[tid - d] : 0;
        __syncthreads();
        scanTmp[tid] += v;
        __syncthreads();
    }
    int run = (tid == 0) ? 0 : scanTmp[tid - 1];
    #pragma unroll
    for (int k = 0; k < 4; ++k) {
        int b = base4 + k;
        if (b < NSLICE) { binStart[b] = run; cursor[b] = run; run += loc[k]; }
    }
    __syncthreads();

    #pragma unroll
    for (int j = 0; j < CHUNK / 256; ++j) {
        if (ent[j] != 0xFFFFFFFFu) {
            int sl = (int)(ent[j] >> (16 + SLICE_SH));
            int pos = atomicAdd(&cursor[sl], 1);
            buf[pos] = ent[j];
        }
    }
    __syncthreads();

    for (int s = tid; s < NSLICE; s += 256) {
        int c = hist[s];
        if (c > 0) gbase[s] = atomicAdd(&tails[s], c);
    }
    __syncthreads();

    for (int i = tid; i < nE; i += 256) {
        unsigned e = buf[i];
        int sl = (int)(e >> (16 + SLICE_SH));
        int di = gbase[sl] + (i - binStart[sl]);
        if (di < CAP) glist[(size_t)sl * CAP + di] = e;
    }
}

// ---------------------------------------------------------------------------
// agg_gemm2: blockIdx.x = slice, blockIdx.y = quarter (16 nodes).
// Filter slice list to own 16 nodes (LDS sort, 4-aligned groups), gather
// V rows with packed uint4 index loads, accumulate relu(U+V) in f16 pairs,
// then fused MFMA GEMM2 vs W2T -> out.  No aggh round-trip, no deg array.
// ---------------------------------------------------------------------------
__global__ __launch_bounds__(256) void agg_gemm2(
    const unsigned* __restrict__ glist, const int* __restrict__ tails,
    const _Float16* __restrict__ Uh, const _Float16* __restrict__ Vh,
    const _Float16* __restrict__ W2T, const float* __restrict__ b2,
    float* __restrict__ out)
{
    __shared__ int h16[16];
    __shared__ int start16[16];
    __shared__ int cur16[16];
    __shared__ unsigned sbuf[CAPQ];       // 4 KB, src indices (4-aligned groups)
    __shared__ _Float16 aggA[16][136];    // 16B-aligned rows, 2-way-free banks

    const int slice = blockIdx.x;
    const int yq    = blockIdx.y;
    const int node0 = (slice << SLICE_SH) + yq * 16;
    const int tid   = threadIdx.x;
    const unsigned* lst = glist + (size_t)slice * CAP;
    const int cnt = min(tails[slice], CAP);

    if (tid < 16) h16[tid] = 0;
    __syncthreads();
    for (int i = tid; i < cnt; i += 256) {
        unsigned e = lst[i];
        int dl = (e >> 16) & 63;
        if ((dl >> 4) == yq) atomicAdd(&h16[dl & 15], 1);
    }
    __syncthreads();
    if (tid == 0) {
        int run = 0;
        #pragma unroll
        for (int b = 0; b < 16; ++b) {
            run = (run + 3) & ~3;            // 16 B-align each group
            start16[b] = run; cur16[b] = run;
            run += h16[b];
        }
    }
    __syncthreads();
    for (int i = tid; i < cnt; i += 256) {
        unsigned e = lst[i];
        int dl = (e >> 16) & 63;
        if ((dl >> 4) == yq) {
            int pos = atomicAdd(&cur16[dl & 15], 1);
            if (pos < CAPQ) sbuf[pos] = e & 0xFFFFu;
        }
    }
    __syncthreads();

    const int wave = tid >> 6;
    const int lane = tid & 63;
    const int quad = lane >> 4;
    const int l15  = lane & 15;
    const int c2   = lane * 2;
    const half2v zero = {(_Float16)0, (_Float16)0};

    // ---- gather + accumulate: wave w owns local nodes 4w..4w+3 ----
    #pragma unroll
    for (int i = 0; i < 4; ++i) {
        const int b = wave * 4 + i;
        const int n = node0 + b;
        half2v u2 = zero, acc2 = zero;
        int gb = start16[b];
        int gc = h16[b];
        if (n < N_NODES) u2 = *(const half2v*)(Uh + (n << 7) + c2);
        else gc = 0;
        int p = gb, pe = min(gb + gc, CAPQ);
        for (; p + 8 <= pe; p += 8) {
            uint4 q0 = *(const uint4*)&sbuf[p];
            uint4 q1 = *(const uint4*)&sbuf[p + 4];
            half2v v0 = *(const half2v*)(Vh + (q0.x << 7) + c2);
            half2v v1 = *(const half2v*)(Vh + (q0.y << 7) + c2);
            half2v v2 = *(const half2v*)(Vh + (q0.z << 7) + c2);
            half2v v3 = *(const half2v*)(Vh + (q0.w << 7) + c2);
            half2v v4 = *(const half2v*)(Vh + (q1.x << 7) + c2);
            half2v v5 = *(const half2v*)(Vh + (q1.y << 7) + c2);
            half2v v6 = *(const half2v*)(Vh + (q1.z << 7) + c2);
            half2v v7 = *(const half2v*)(Vh + (q1.w << 7) + c2);
            half2v m0 = __builtin_elementwise_max(u2 + v0, zero);
            half2v m1 = __builtin_elementwise_max(u2 + v1, zero);
            half2v m2 = __builtin_elementwise_max(u2 + v2, zero);
            half2v m3 = __builtin_elementwise_max(u2 + v3, zero);
            half2v m4 = __builtin_elementwise_max(u2 + v4, zero);
            half2v m5 = __builtin_elementwise_max(u2 + v5, zero);
            half2v m6 = __builtin_elementwise_max(u2 + v6, zero);
            half2v m7 = __builtin_elementwise_max(u2 + v7, zero);
            acc2 += ((m0 + m1) + (m2 + m3)) + ((m4 + m5) + (m6 + m7));
        }
        for (; p + 4 <= pe; p += 4) {
            uint4 q0 = *(const uint4*)&sbuf[p];
            half2v v0 = *(const half2v*)(Vh + (q0.x << 7) + c2);
            half2v v1 = *(const half2v*)(Vh + (q0.y << 7) + c2);
            half2v v2 = *(const half2v*)(Vh + (q0.z << 7) + c2);
            half2v v3 = *(const half2v*)(Vh + (q0.w << 7) + c2);
            acc2 += (__builtin_elementwise_max(u2 + v0, zero)
                   + __builtin_elementwise_max(u2 + v1, zero))
                  + (__builtin_elementwise_max(u2 + v2, zero)
                   + __builtin_elementwise_max(u2 + v3, zero));
        }
        for (; p < pe; ++p) {
            int s0 = (int)sbuf[p];
            half2v v0 = *(const half2v*)(Vh + (s0 << 7) + c2);
            acc2 += __builtin_elementwise_max(u2 + v0, zero);
        }
        *(half2v*)&aggA[b][c2] = acc2;
    }
    __syncthreads();

    // ---- fused GEMM2: out[16 rows][wave's 32 cols] = aggA @ W2T^T + deg*b2
    f32x4 accm[2];
    {   f32x4 z = {0.f,0.f,0.f,0.f}; accm[0] = z; accm[1] = z; }
    #pragma unroll
    for (int t = 0; t < 4; ++t) {
        const int k0 = 32 * t + quad * 8;
        half8 af = *(const half8*)&aggA[l15][k0];
        #pragma unroll
        for (int c = 0; c < 2; ++c) {
            const int ct = wave * 2 + c;
            half8 bf = *(const half8*)(W2T + ((ct * 16 + l15) << 7) + k0);
            accm[c] = __builtin_amdgcn_mfma_f32_16x16x32_f16(af, bf, accm[c], 0, 0, 0);
        }
    }
    int dgj[4];
    #pragma unroll
    for (int j = 0; j < 4; ++j) dgj[j] = h16[quad * 4 + j];

    #pragma unroll
    for (int c = 0; c < 2; ++c) {
        const int col = (wave * 2 + c) * 16 + l15;
        const float bb = b2[col];
        #pragma unroll
        for (int j = 0; j < 4; ++j) {
            const int n = node0 + quad * 4 + j;
            if (n < N_NODES)
                out[(size_t)n * OUT_DIM + col] = accm[c][j] + bb * (float)dgj[j];
        }
    }
}

// ---------------------------------------------------------------------------
extern "C" void kernel_launch(void* const* d_in, const int* in_sizes, int n_in,
                              void* d_out, int out_size, void* d_ws, size_t ws_size,
                              hipStream_t stream)
{
    const float* x       = (const float*)d_in[0];
    const float* scalars = (const float*)d_in[1];
    const int*   batch   = (const int*)d_in[2];
    const int*   ei      = (const int*)d_in[3];
    const float* W1      = (const float*)d_in[4];
    const float* b1      = (const float*)d_in[5];
    const float* W2      = (const float*)d_in[6];
    const float* b2      = (const float*)d_in[7];
    float*       out     = (float*)d_out;

    // ws: Uh | Vh | glist | WfT | W2T | SG | tails  (~34 MB)
    _Float16* Uh    = (_Float16*)d_ws;
    _Float16* Vh    = Uh + (size_t)N_NODES * HIDDEN;
    unsigned* glist = (unsigned*)(Vh + (size_t)N_NODES * HIDDEN);
    _Float16* WfT   = (_Float16*)(glist + (size_t)NSLICE * CAP);
    _Float16* W2T   = WfT + 256 * 64;
    float*    SG    = (float*)(W2T + 128 * 128);
    int*      tails = (int*)(SG + 64 * UV_DIM);

    prep_kernel<<<64, 256, 0, stream>>>(W1, b1, W2, scalars, WfT, W2T, SG, tails);

    gemm1_bin<<<G1_BLOCKS + BIN_BLOCKS, 256, 0, stream>>>(
        x, batch, WfT, SG, Uh, Vh, ei, tails, glist);

    agg_gemm2<<<dim3(NSLICE, 4), 256, 0, stream>>>(
        glist, tails, Uh, Vh, W2T, b2, out);
}